// Round 18
// baseline (193.335 us; speedup 1.0000x reference)
//
#include <hip/hip_runtime.h>
#include <hip/hip_bf16.h>
#include <stdint.h>

typedef unsigned short u16;
typedef float f32x4 __attribute__((ext_vector_type(4)));
typedef __bf16 bf16x8 __attribute__((ext_vector_type(8)));
typedef unsigned short u16x8 __attribute__((ext_vector_type(8)));
typedef unsigned short u16x4 __attribute__((ext_vector_type(4)));
typedef float f32x4v __attribute__((ext_vector_type(4)));

#define T_SEQ 2048

__device__ __forceinline__ u16 f2bf(float f) {
    unsigned int u = __float_as_uint(f);
    unsigned int r = (u + 0x7fffu + ((u >> 16) & 1u)) >> 16;
    return (u16)r;
}
__device__ __forceinline__ float bf2f(u16 b) {
    return __uint_as_float(((unsigned int)b) << 16);
}

__device__ __forceinline__ void gload_lds16(const void* g, void* l) {
    __builtin_amdgcn_global_load_lds(
        (__attribute__((address_space(1))) void*)(g),
        (__attribute__((address_space(3))) void*)(l), 16, 0, 0);
}

// ---------- fused preprocessing: x cast (blocks 0..4095) + W transposes ----------
__global__ void prep_all(const float* __restrict__ x, u16* __restrict__ xbf,
                         const float* __restrict__ Wq, const float* __restrict__ Wk,
                         const float* __restrict__ Wv, const float* __restrict__ Wp,
                         u16* __restrict__ WtQKV, u16* __restrict__ WtP) {
    __shared__ alignas(16) float sW[64 * 68];
    const int t = threadIdx.x;
    const int bid = blockIdx.x;
    if (bid < 4096) {
        int i = bid * 256 + t;
        const f32x4v* p = (const f32x4v*)(x + (size_t)i * 8);
        f32x4v a = p[0], bb = p[1];
        u16x8 v;
        v[0]=f2bf(a.x); v[1]=f2bf(a.y); v[2]=f2bf(a.z); v[3]=f2bf(a.w);
        v[4]=f2bf(bb.x); v[5]=f2bf(bb.y); v[6]=f2bf(bb.z); v[7]=f2bf(bb.w);
        *(u16x8*)(xbf + (size_t)i * 8) = v;
        return;
    }
    const int rem = bid - 4096;
    const int y = rem >> 5;
    const float* W; u16* dst; int N; int n0;
    if (y < 32)      { W = Wq; dst = WtQKV;                       N = 2048; n0 = y * 64; }
    else if (y < 40) { W = Wk; dst = WtQKV + (size_t)2048 * 2048; N = 512;  n0 = (y - 32) * 64; }
    else if (y < 48) { W = Wv; dst = WtQKV + (size_t)2560 * 2048; N = 512;  n0 = (y - 40) * 64; }
    else             { W = Wp; dst = WtP;                         N = 2048; n0 = (y - 48) * 64; }
    const int k0 = (rem & 31) * 64;
#pragma unroll
    for (int i = 0; i < 4; i++) {
        int kr = i * 16 + (t >> 4), nc = (t & 15) * 4;
        *(f32x4v*)&sW[kr * 68 + nc] = *(const f32x4v*)&W[(size_t)(k0 + kr) * N + n0 + nc];
    }
    __syncthreads();
#pragma unroll
    for (int i = 0; i < 2; i++) {
        int nr = i * 32 + (t >> 3), kc = (t & 7) * 8;
        u16x8 v;
#pragma unroll
        for (int j = 0; j < 8; j++) v[j] = f2bf(sW[(kc + j) * 68 + nr]);
        *(u16x8*)&dst[(size_t)(n0 + nr) * 2048 + k0 + kc] = v;
    }
}

// ======== shared staging helpers (XOR-swizzled content, linear LDS) ========
__device__ __forceinline__ void stage_rows(const u16* g, u16* lds, int R, int kcol0, int K, int t) {
    int row = R + (t >> 3);
    int u = t & 7;
    gload_lds16(g + (size_t)row * K + kcol0 + ((u ^ (row & 7)) * 8), lds + row * 64 + u * 8);
}
__device__ __forceinline__ void stage_half256(const u16* g, u16* lds, int half, int j, int kcol0, int K, int t) {
    int idx = j * 512 + t;
    int group = idx >> 8;
    int r32 = (idx >> 3) & 31;
    int row = group * 64 + half * 32 + r32;
    int u = idx & 7;
    gload_lds16(g + (size_t)row * K + kcol0 + ((u ^ (row & 7)) * 8), lds + row * 64 + u * 8);
}
__device__ __forceinline__ bf16x8 lds_ld(const u16* lds, int row, int kc, int hl) {
    return *(const bf16x8*)&lds[row * 64 + (((kc * 4 + hl) ^ (row & 7)) * 8)];
}

// ================= QKV GEMM: 256x192 tiles, 256 blocks (1/CU) =================
__global__ __launch_bounds__(512, 2) void gemm_qkv(const u16* __restrict__ A, const u16* __restrict__ Bt,
                                                   u16* __restrict__ C, int M, int N, int K) {
    __shared__ alignas(16) u16 ldsA[2][256 * 64];
    __shared__ alignas(16) u16 ldsB[2][192 * 64];
    const int t = threadIdx.x, wave = t >> 6, lane = t & 63;
    const int l15 = lane & 15, hl = lane >> 4;
    const int wr = wave >> 2, wc = wave & 3;

    const int f = blockIdx.x;
    const int swz = (f & 7) * 32 + (f >> 3);
    const int bx = swz & 15, by = swz >> 4;
    const int m0 = bx * 256, n0 = by * 192;

    const u16* gA = A + (size_t)m0 * K;
    const u16* gB = Bt + (size_t)n0 * K;

    f32x4 acc[8][3];
    f32x4 z = {0.f, 0.f, 0.f, 0.f};
#pragma unroll
    for (int m = 0; m < 8; m++)
#pragma unroll
        for (int n = 0; n < 3; n++) acc[m][n] = z;

    stage_rows(gA, ldsA[0], 0, 0, K, t);
    stage_rows(gA, ldsA[0], 128, 0, K, t);
    stage_rows(gB, ldsB[0], 0, 0, K, t);
    stage_rows(gB, ldsB[0], 64, 0, K, t);
    stage_rows(gB, ldsB[0], 128, 0, K, t);
    stage_rows(gA, ldsA[0], 64, 0, K, t);
    stage_rows(gA, ldsA[0], 192, 0, K, t);

    const int KT = K >> 6;
    for (int kt = 0; kt < KT; ++kt) {
        const int c = kt & 1;
        const int kn = (kt + 1 < KT) ? (kt + 1) * 64 : kt * 64;
        const u16* lAc = ldsA[c];
        const u16* lBc = ldsB[c];
        u16* lAn = ldsA[c ^ 1];
        u16* lBn = ldsB[c ^ 1];

        bf16x8 aF[4][2], bF[3][2];

        asm volatile("s_waitcnt vmcnt(2)" ::: "memory");
        __builtin_amdgcn_s_barrier();
#pragma unroll
        for (int mi = 0; mi < 4; mi++)
#pragma unroll
            for (int kc = 0; kc < 2; kc++)
                aF[mi][kc] = lds_ld(lAc, wr * 128 + mi * 16 + l15, kc, hl);
#pragma unroll
        for (int n = 0; n < 3; n++)
#pragma unroll
            for (int kc = 0; kc < 2; kc++)
                bF[n][kc] = lds_ld(lBc, wc * 48 + n * 16 + l15, kc, hl);
        stage_rows(gA, lAn, 0, kn, K, t);
        stage_rows(gA, lAn, 128, kn, K, t);
        stage_rows(gB, lBn, 0, kn, K, t);
        __builtin_amdgcn_s_setprio(1);
#pragma unroll
        for (int mi = 0; mi < 4; mi++)
#pragma unroll
            for (int n = 0; n < 3; n++)
#pragma unroll
                for (int kc = 0; kc < 2; kc++)
                    acc[mi][n] = __builtin_amdgcn_mfma_f32_16x16x32_bf16(aF[mi][kc], bF[n][kc], acc[mi][n], 0, 0, 0);
        __builtin_amdgcn_s_setprio(0);

        asm volatile("s_waitcnt vmcnt(3)" ::: "memory");
        __builtin_amdgcn_s_barrier();
#pragma unroll
        for (int mi = 0; mi < 4; mi++)
#pragma unroll
            for (int kc = 0; kc < 2; kc++)
                aF[mi][kc] = lds_ld(lAc, wr * 128 + 64 + mi * 16 + l15, kc, hl);
        stage_rows(gB, lBn, 64, kn, K, t);
        stage_rows(gB, lBn, 128, kn, K, t);
        stage_rows(gA, lAn, 64, kn, K, t);
        stage_rows(gA, lAn, 192, kn, K, t);
        __builtin_amdgcn_s_setprio(1);
#pragma unroll
        for (int mi = 0; mi < 4; mi++)
#pragma unroll
            for (int n = 0; n < 3; n++)
#pragma unroll
                for (int kc = 0; kc < 2; kc++)
                    acc[4 + mi][n] = __builtin_amdgcn_mfma_f32_16x16x32_bf16(aF[mi][kc], bF[n][kc], acc[4 + mi][n], 0, 0, 0);
        __builtin_amdgcn_s_setprio(0);
    }

#pragma unroll
    for (int m = 0; m < 8; m++)
#pragma unroll
        for (int n = 0; n < 3; n++)
#pragma unroll
            for (int r = 0; r < 4; r++) {
                int row = m0 + wr * 128 + m * 16 + hl * 4 + r;
                int col = n0 + wc * 48 + n * 16 + l15;
                C[(size_t)row * N + col] = f2bf(acc[m][n][r]);
            }
}

// ================= proj GEMM: 128x256 tiles, 256 blocks (1/CU), f32 out =================
__global__ __launch_bounds__(512, 2) void gemm_proj(const u16* __restrict__ A, const u16* __restrict__ Bt,
                                                    float* __restrict__ C, int M, int N, int K) {
    __shared__ alignas(16) u16 ldsA[2][128 * 64];
    __shared__ alignas(16) u16 ldsB[2][256 * 64];
    const int t = threadIdx.x, wave = t >> 6, lane = t & 63;
    const int l15 = lane & 15, hl = lane >> 4;
    const int wr = wave >> 2, wc = wave & 3;

    const int f = blockIdx.x;
    const int swz = (f & 7) * 32 + (f >> 3);
    const int bx = swz & 31, by = swz >> 5;
    const int m0 = bx * 128, n0 = by * 256;

    const u16* gA = A + (size_t)m0 * K;
    const u16* gB = Bt + (size_t)n0 * K;

    f32x4 acc[4][4];
    f32x4 z = {0.f, 0.f, 0.f, 0.f};
#pragma unroll
    for (int m = 0; m < 4; m++)
#pragma unroll
        for (int n = 0; n < 4; n++) acc[m][n] = z;

    stage_rows(gA, ldsA[0], 0, 0, K, t);
    stage_rows(gA, ldsA[0], 64, 0, K, t);
    stage_half256(gB, ldsB[0], 0, 0, 0, K, t);
    stage_half256(gB, ldsB[0], 0, 1, 0, K, t);
    stage_half256(gB, ldsB[0], 1, 0, 0, K, t);
    stage_half256(gB, ldsB[0], 1, 1, 0, K, t);

    const int KT = K >> 6;
    for (int kt = 0; kt < KT; ++kt) {
        const int c = kt & 1;
        const int kn = (kt + 1 < KT) ? (kt + 1) * 64 : kt * 64;
        const u16* lAc = ldsA[c];
        const u16* lBc = ldsB[c];
        u16* lAn = ldsA[c ^ 1];
        u16* lBn = ldsB[c ^ 1];

        bf16x8 aF[4][2], bF[2][2];

        asm volatile("s_waitcnt vmcnt(2)" ::: "memory");
        __builtin_amdgcn_s_barrier();
#pragma unroll
        for (int mi = 0; mi < 4; mi++)
#pragma unroll
            for (int kc = 0; kc < 2; kc++)
                aF[mi][kc] = lds_ld(lAc, wr * 64 + mi * 16 + l15, kc, hl);
#pragma unroll
        for (int n = 0; n < 2; n++)
#pragma unroll
            for (int kc = 0; kc < 2; kc++)
                bF[n][kc] = lds_ld(lBc, wc * 64 + n * 16 + l15, kc, hl);
        stage_rows(gA, lAn, 0, kn, K, t);
        stage_rows(gA, lAn, 64, kn, K, t);
        stage_half256(gB, lBn, 0, 0, kn, K, t);
        stage_half256(gB, lBn, 0, 1, kn, K, t);
        __builtin_amdgcn_s_setprio(1);
#pragma unroll
        for (int mi = 0; mi < 4; mi++)
#pragma unroll
            for (int n = 0; n < 2; n++)
#pragma unroll
                for (int kc = 0; kc < 2; kc++)
                    acc[mi][n] = __builtin_amdgcn_mfma_f32_16x16x32_bf16(aF[mi][kc], bF[n][kc], acc[mi][n], 0, 0, 0);
        __builtin_amdgcn_s_setprio(0);

        asm volatile("s_waitcnt vmcnt(4)" ::: "memory");
        __builtin_amdgcn_s_barrier();
#pragma unroll
        for (int n = 0; n < 2; n++)
#pragma unroll
            for (int kc = 0; kc < 2; kc++)
                bF[n][kc] = lds_ld(lBc, wc * 64 + 32 + n * 16 + l15, kc, hl);
        stage_half256(gB, lBn, 1, 0, kn, K, t);
        stage_half256(gB, lBn, 1, 1, kn, K, t);
        __builtin_amdgcn_s_setprio(1);
#pragma unroll
        for (int mi = 0; mi < 4; mi++)
#pragma unroll
            for (int n = 0; n < 2; n++)
#pragma unroll
                for (int kc = 0; kc < 2; kc++)
                    acc[mi][2 + n] = __builtin_amdgcn_mfma_f32_16x16x32_bf16(aF[mi][kc], bF[n][kc], acc[mi][2 + n], 0, 0, 0);
        __builtin_amdgcn_s_setprio(0);
    }

#pragma unroll
    for (int m = 0; m < 4; m++)
#pragma unroll
        for (int n = 0; n < 4; n++)
#pragma unroll
            for (int r = 0; r < 4; r++) {
                int row = m0 + wr * 64 + m * 16 + hl * 4 + r;
                int col = n0 + wc * 64 + n * 16 + l15;
                C[(size_t)row * N + col] = acc[m][n][r];
            }
}

// ---------------- fused RoPE (vectorized x4, in place) + V transpose ----------------
__global__ void rope_vtrans(u16* __restrict__ qkv, u16* __restrict__ vt,
                            const int* __restrict__ pos) {
    __shared__ alignas(16) u16 sT[64 * 72];
    const int t = threadIdx.x;
    if (blockIdx.x < 512) {
        const int f = blockIdx.x;
        const int t0 = (f & 31) * 64;
        const int d0 = ((f >> 5) & 1) * 64;
        const int kh = (f >> 6) & 3, b = f >> 8;
#pragma unroll
        for (int i = 0; i < 2; i++) {
            int tr = i * 32 + (t >> 3), dc = (t & 7) * 8;
            *(u16x8*)&sT[tr * 72 + dc] =
                *(const u16x8*)&qkv[(size_t)(b * T_SEQ + t0 + tr) * 3072 + 2560 + kh * 128 + d0 + dc];
        }
        __syncthreads();
#pragma unroll
        for (int i = 0; i < 2; i++) {
            int dr = i * 32 + (t >> 3), tc = (t & 7) * 8;
            u16x8 v;
#pragma unroll
            for (int j = 0; j < 8; j++) v[j] = sT[(tc + j) * 72 + dr];
            *(u16x8*)&vt[((size_t)(b * 4 + kh) * 128 + d0 + dr) * 2048 + t0 + tc] = v;
        }
    } else {
        int tid = (blockIdx.x - 512) * 256 + t;
        int j4 = tid & 15;
        int rest = tid >> 4;
        int slice = rest % 20;
        int row = rest / 20;
        if (row >= 2 * T_SEQ) return;
        float tpos = (float)((row % T_SEQ) + pos[0]);
        int base = (slice < 16) ? slice * 128 : 2048 + (slice - 16) * 128;
        u16* p = qkv + (size_t)row * 3072 + base + j4 * 4;
        u16x4 lo = *(const u16x4*)p;
        u16x4 hi = *(const u16x4*)(p + 64);
        const float c0 = 0.20762050593045702f;   // log2(10000)/64
        u16x4 olo, ohi;
#pragma unroll
        for (int e = 0; e < 4; e++) {
            int i = (j4 * 4 + e) >> 1;
            float fA = tpos * exp2f(-(float)i * c0);
            float fB = tpos * exp2f(-(float)(32 + i) * c0);
            float x1 = bf2f(lo[e]), x2 = bf2f(hi[e]);
            olo[e] = f2bf(x1 * cosf(fA) - x2 * sinf(fA));
            ohi[e] = f2bf(x2 * cosf(fB) + x1 * sinf(fB));
        }
        *(u16x4*)p = olo;
        *(u16x4*)(p + 64) = ohi;
    }
}

// ---------------- causal GQA flash attention: 8 waves x 16 q-rows ----------------
// 2-barrier counted schedule: K+V double-buffered, no vmcnt(0) in loop.
// Per tile: stageK(t+1) | vmcnt(4)+bar | stageV(t+1) | QK^T | softmax | vmcnt(4)+bar | PV.
// sP stride-64 with unit^row XOR swizzle (wave-private). LDS = 32+32+16 = 80 KB.
__global__ __launch_bounds__(512, 4) void attn(const u16* __restrict__ qkv,
                                               const u16* __restrict__ vt,
                                               u16* __restrict__ out) {
    __shared__ alignas(16) u16 sK[2][8192];       // [64][128] XOR-swizzled content
    __shared__ alignas(16) u16 sV[2][8192];       // [128][64] XOR-swizzled content
    __shared__ alignas(16) __bf16 sP[128 * 64];   // stride 64, unit^(row&7) swizzle
    const int t = threadIdx.x, wave = t >> 6, lane = t & 63;
    const int l15 = lane & 15, hl = lane >> 4;

    const int f = blockIdx.x;
    const int sel = f >> 8, u = f & 255;
    const int bkh = u & 7, b = bkh >> 2, kh = bkh & 3;
    const int h = kh * 4 + ((u >> 3) & 3);
    const int j = u >> 5;
    const int a = sel ? (15 - j) : j;
    const int q0 = a * 128;
    const int nt = 2 * a + 2;

    const float sc = 0.08838834764831845f;

    bf16x8 qf[4];
#pragma unroll
    for (int c = 0; c < 4; c++) {
        const u16* qp = qkv + (size_t)(b * T_SEQ + q0 + wave * 16 + l15) * 3072
                        + h * 128 + c * 32 + hl * 8;
        u16x8 raw = *(const u16x8*)qp;
        u16x8 sv_;
#pragma unroll
        for (int e = 0; e < 8; e++) sv_[e] = f2bf(bf2f(raw[e]) * sc);
        qf[c] = *(bf16x8*)&sv_;
    }

    u16x8 onesu;
#pragma unroll
    for (int e = 0; e < 8; e++) onesu[e] = 0x3F80;
    const bf16x8 onesf = *(bf16x8*)&onesu;

    float mrow[4];
    f32x4 o[8];
    f32x4 osum;
    f32x4 z = {0.f, 0.f, 0.f, 0.f};
#pragma unroll
    for (int r = 0; r < 4; r++) mrow[r] = -1e30f;
    osum = z;
#pragma unroll
    for (int n8 = 0; n8 < 8; n8++) o[n8] = z;

    asm volatile("s_waitcnt vmcnt(0)" ::: "memory");

    const u16* kgbase = qkv + (size_t)(b * T_SEQ) * 3072 + 2048 + kh * 128;
    const u16* vgbase = vt + (size_t)(b * 4 + kh) * 128 * 2048;

    // prologue: stage K(0) then V(0) into buf 0 (2+2 gloads/thread, issue order fixed)
#pragma unroll
    for (int p = 0; p < 2; p++) {
        int i = p * 512 + t;
        int row = i >> 4, c = i & 15;
        gload_lds16(kgbase + (size_t)row * 3072 + ((c ^ (row & 7)) * 8), (u16*)sK[0] + i * 8);
    }
#pragma unroll
    for (int p = 0; p < 2; p++) {
        int i = p * 512 + t;
        int row = i >> 3, c = i & 7;
        gload_lds16(vgbase + (size_t)row * 2048 + ((c ^ (row & 7)) * 8), (u16*)sV[0] + i * 8);
    }

    int cur = 0;
    for (int it = 0; it < nt; ++it) {
        const int kv0 = it * 64;
        const int kvn = (it + 1 < nt) ? kv0 + 64 : kv0;

        // stage K(t+1) -> sK[cur^1]  (WAR protected by prev iter's 2nd barrier)
#pragma unroll
        for (int p = 0; p < 2; p++) {
            int i = p * 512 + t;
            int row = i >> 4, c = i & 15;
            gload_lds16(kgbase + (size_t)(kvn + row) * 3072 + ((c ^ (row & 7)) * 8),
                        (u16*)sK[cur ^ 1] + i * 8);
        }
        asm volatile("s_waitcnt vmcnt(4)" ::: "memory");   // K(t) landed; V(t)+K(t+1) in flight
        __builtin_amdgcn_s_barrier();

        // stage V(t+1) -> sV[cur^1]  (WAR protected by the barrier just passed)
#pragma unroll
        for (int p = 0; p < 2; p++) {
            int i = p * 512 + t;
            int row = i >> 3, c = i & 7;
            gload_lds16(vgbase + (size_t)row * 2048 + kvn + ((c ^ (row & 7)) * 8),
                        (u16*)sV[cur ^ 1] + i * 8);
        }

        // S = Q K^T  (16 rows x 64 cols per wave)
        f32x4 sA[4];
#pragma unroll
        for (int n = 0; n < 4; n++) sA[n] = z;
#pragma unroll
        for (int n = 0; n < 4; n++)
#pragma unroll
            for (int c = 0; c < 4; c++) {
                int row = n * 16 + l15;
                bf16x8 kf = *(const bf16x8*)&sK[cur][row * 128 + (((c * 4 + hl) ^ (row & 7)) * 8)];
                sA[n] = __builtin_amdgcn_mfma_f32_16x16x32_bf16(qf[c], kf, sA[n], 0, 0, 0);
            }

        // online softmax: interior tiles skip causal mask entirely (wave-uniform)
        const bool full = (kv0 + 63 <= q0 + wave * 16);
        if (full) {
#pragma unroll
            for (int r = 0; r < 4; r++) {
                float pmax = fmaxf(fmaxf(sA[0][r], sA[1][r]), fmaxf(sA[2][r], sA[3][r]));
                if (__builtin_expect(__any(pmax > mrow[r] + 8.f), 0)) {
                    float mx = pmax;
#pragma unroll
                    for (int off = 1; off < 16; off <<= 1) mx = fmaxf(mx, __shfl_xor(mx, off));
                    float mnew = fmaxf(mrow[r], mx);
                    float alpha = __expf(mrow[r] - mnew);
                    mrow[r] = mnew;
#pragma unroll
                    for (int n8 = 0; n8 < 8; n8++) o[n8][r] *= alpha;
                    osum[r] *= alpha;
                }
                const int prow = wave * 16 + hl * 4 + r;
                const int p7 = prow & 7;
#pragma unroll
                for (int n = 0; n < 4; n++)
                    sP[prow * 64 + (((n * 2 + (l15 >> 3)) ^ p7) << 3) + (l15 & 7)] =
                        (__bf16)__expf(sA[n][r] - mrow[r]);
            }
        } else {
#pragma unroll
            for (int r = 0; r < 4; r++) {
                const int grow = q0 + wave * 16 + hl * 4 + r;
                float mv[4];
#pragma unroll
                for (int n = 0; n < 4; n++)
                    mv[n] = (kv0 + n * 16 + l15 <= grow) ? sA[n][r] : -1e30f;
                float pmax = fmaxf(fmaxf(mv[0], mv[1]), fmaxf(mv[2], mv[3]));
                if (__builtin_expect(__any(pmax > mrow[r] + 8.f), 0)) {
                    float mx = pmax;
#pragma unroll
                    for (int off = 1; off < 16; off <<= 1) mx = fmaxf(mx, __shfl_xor(mx, off));
                    float mnew = fmaxf(mrow[r], mx);
                    float alpha = __expf(mrow[r] - mnew);
                    mrow[r] = mnew;
#pragma unroll
                    for (int n8 = 0; n8 < 8; n8++) o[n8][r] *= alpha;
                    osum[r] *= alpha;
                }
                const int prow = wave * 16 + hl * 4 + r;
                const int p7 = prow & 7;
#pragma unroll
                for (int n = 0; n < 4; n++)
                    sP[prow * 64 + (((n * 2 + (l15 >> 3)) ^ p7) << 3) + (l15 & 7)] =
                        (__bf16)__expf(mv[n] - mrow[r]);
            }
        }

        asm volatile("s_waitcnt vmcnt(4)" ::: "memory");   // V(t) landed; K(t+1)+V(t+1) in flight
        __builtin_amdgcn_s_barrier();

        // P fragments (wave-private sP; compiler inserts lgkmcnt for own writes)
        bf16x8 pa[2];
#pragma unroll
        for (int k2 = 0; k2 < 2; k2++)
            pa[k2] = *(const bf16x8*)&sP[(wave * 16 + l15) * 64 + (((k2 * 4 + hl) ^ (l15 & 7)) << 3)];
#pragma unroll
        for (int k2 = 0; k2 < 2; k2++)
            osum = __builtin_amdgcn_mfma_f32_16x16x32_bf16(pa[k2], onesf, osum, 0, 0, 0);
#pragma unroll
        for (int n8 = 0; n8 < 8; n8++)
#pragma unroll
            for (int k2 = 0; k2 < 2; k2++) {
                int d = n8 * 16 + l15;
                bf16x8 vf = *(const bf16x8*)&sV[cur][d * 64 + (((k2 * 4 + hl) ^ (d & 7)) * 8)];
                o[n8] = __builtin_amdgcn_mfma_f32_16x16x32_bf16(pa[k2], vf, o[n8], 0, 0, 0);
            }
        cur ^= 1;
    }

#pragma unroll
    for (int r = 0; r < 4; r++) {
        float inv = 1.f / osum[r];
        int orow = b * T_SEQ + q0 + wave * 16 + hl * 4 + r;
#pragma unroll
        for (int n8 = 0; n8 < 8; n8++)
            out[(size_t)orow * 2048 + h * 128 + n8 * 16 + l15] = f2bf(o[n8][r] * inv);
    }
}

extern "C" void kernel_launch(void* const* d_in, const int* in_sizes, int n_in,
                              void* d_out, int out_size, void* d_ws, size_t ws_size,
                              hipStream_t stream) {
    const float* x  = (const float*)d_in[0];
    const float* Wq = (const float*)d_in[1];
    const float* Wk = (const float*)d_in[2];
    const float* Wv = (const float*)d_in[3];
    const float* Wp = (const float*)d_in[4];
    const int*   pos = (const int*)d_in[5];

    char* ws = (char*)d_ws;
    u16* xbf   = (u16*)(ws);                        // 4096*2048 bf16
    u16* WtQKV = (u16*)(ws + 16777216);             // 3072*2048 bf16
    u16* WtP   = (u16*)(ws + 29360128);             // 2048*2048 bf16
    u16* QKV   = (u16*)(ws + 37748736);             // 4096*3072 bf16
    u16* Vt    = (u16*)(ws + 62914560);             // 2*4*128*2048 bf16
    u16* AO    = (u16*)(ws + 67108864);             // 4096*2048 bf16

    prep_all<<<4096 + 2560, 256, 0, stream>>>(x, xbf, Wq, Wk, Wv, Wp, WtQKV, WtP);
    gemm_qkv<<<256, 512, 0, stream>>>(xbf, WtQKV, QKV, 4096, 3072, 2048);
    rope_vtrans<<<512 + 5120, 256, 0, stream>>>(QKV, Vt, pos);
    attn<<<512, 512, 0, stream>>>(QKV, Vt, AO);
    gemm_proj<<<256, 512, 0, stream>>>(AO, WtP, (float*)d_out, 4096, 2048, 2048);
}

// Round 19
// 183.102 us; speedup vs baseline: 1.0559x; 1.0559x over previous
//
#include <hip/hip_runtime.h>
#include <hip/hip_bf16.h>
#include <stdint.h>

typedef unsigned short u16;
typedef float f32x4 __attribute__((ext_vector_type(4)));
typedef __bf16 bf16x8 __attribute__((ext_vector_type(8)));
typedef unsigned short u16x8 __attribute__((ext_vector_type(8)));
typedef unsigned short u16x4 __attribute__((ext_vector_type(4)));
typedef float f32x4v __attribute__((ext_vector_type(4)));

#define T_SEQ 2048

__device__ __forceinline__ u16 f2bf(float f) {
    unsigned int u = __float_as_uint(f);
    unsigned int r = (u + 0x7fffu + ((u >> 16) & 1u)) >> 16;
    return (u16)r;
}
__device__ __forceinline__ float bf2f(u16 b) {
    return __uint_as_float(((unsigned int)b) << 16);
}

__device__ __forceinline__ void gload_lds16(const void* g, void* l) {
    __builtin_amdgcn_global_load_lds(
        (__attribute__((address_space(1))) void*)(g),
        (__attribute__((address_space(3))) void*)(l), 16, 0, 0);
}

// ---------- fused preprocessing: x cast (blocks 0..4095) + W transposes ----------
__global__ void prep_all(const float* __restrict__ x, u16* __restrict__ xbf,
                         const float* __restrict__ Wq, const float* __restrict__ Wk,
                         const float* __restrict__ Wv, const float* __restrict__ Wp,
                         u16* __restrict__ WtQKV, u16* __restrict__ WtP) {
    __shared__ alignas(16) float sW[64 * 68];
    const int t = threadIdx.x;
    const int bid = blockIdx.x;
    if (bid < 4096) {
        int i = bid * 256 + t;
        const f32x4v* p = (const f32x4v*)(x + (size_t)i * 8);
        f32x4v a = p[0], bb = p[1];
        u16x8 v;
        v[0]=f2bf(a.x); v[1]=f2bf(a.y); v[2]=f2bf(a.z); v[3]=f2bf(a.w);
        v[4]=f2bf(bb.x); v[5]=f2bf(bb.y); v[6]=f2bf(bb.z); v[7]=f2bf(bb.w);
        *(u16x8*)(xbf + (size_t)i * 8) = v;
        return;
    }
    const int rem = bid - 4096;
    const int y = rem >> 5;
    const float* W; u16* dst; int N; int n0;
    if (y < 32)      { W = Wq; dst = WtQKV;                       N = 2048; n0 = y * 64; }
    else if (y < 40) { W = Wk; dst = WtQKV + (size_t)2048 * 2048; N = 512;  n0 = (y - 32) * 64; }
    else if (y < 48) { W = Wv; dst = WtQKV + (size_t)2560 * 2048; N = 512;  n0 = (y - 40) * 64; }
    else             { W = Wp; dst = WtP;                         N = 2048; n0 = (y - 48) * 64; }
    const int k0 = (rem & 31) * 64;
#pragma unroll
    for (int i = 0; i < 4; i++) {
        int kr = i * 16 + (t >> 4), nc = (t & 15) * 4;
        *(f32x4v*)&sW[kr * 68 + nc] = *(const f32x4v*)&W[(size_t)(k0 + kr) * N + n0 + nc];
    }
    __syncthreads();
#pragma unroll
    for (int i = 0; i < 2; i++) {
        int nr = i * 32 + (t >> 3), kc = (t & 7) * 8;
        u16x8 v;
#pragma unroll
        for (int j = 0; j < 8; j++) v[j] = f2bf(sW[(kc + j) * 68 + nr]);
        *(u16x8*)&dst[(size_t)(n0 + nr) * 2048 + k0 + kc] = v;
    }
}

// ======== shared staging helpers (XOR-swizzled content, linear LDS) ========
__device__ __forceinline__ void stage_rows(const u16* g, u16* lds, int R, int kcol0, int K, int t) {
    int row = R + (t >> 3);
    int u = t & 7;
    gload_lds16(g + (size_t)row * K + kcol0 + ((u ^ (row & 7)) * 8), lds + row * 64 + u * 8);
}
__device__ __forceinline__ void stage_half256(const u16* g, u16* lds, int half, int j, int kcol0, int K, int t) {
    int idx = j * 512 + t;
    int group = idx >> 8;
    int r32 = (idx >> 3) & 31;
    int row = group * 64 + half * 32 + r32;
    int u = idx & 7;
    gload_lds16(g + (size_t)row * K + kcol0 + ((u ^ (row & 7)) * 8), lds + row * 64 + u * 8);
}
__device__ __forceinline__ bf16x8 lds_ld(const u16* lds, int row, int kc, int hl) {
    return *(const bf16x8*)&lds[row * 64 + (((kc * 4 + hl) ^ (row & 7)) * 8)];
}

// ================= QKV GEMM: 256x192 tiles, 256 blocks (1/CU) =================
__global__ __launch_bounds__(512, 2) void gemm_qkv(const u16* __restrict__ A, const u16* __restrict__ Bt,
                                                   u16* __restrict__ C, int M, int N, int K) {
    __shared__ alignas(16) u16 ldsA[2][256 * 64];
    __shared__ alignas(16) u16 ldsB[2][192 * 64];
    const int t = threadIdx.x, wave = t >> 6, lane = t & 63;
    const int l15 = lane & 15, hl = lane >> 4;
    const int wr = wave >> 2, wc = wave & 3;

    const int f = blockIdx.x;
    const int swz = (f & 7) * 32 + (f >> 3);
    const int bx = swz & 15, by = swz >> 4;
    const int m0 = bx * 256, n0 = by * 192;

    const u16* gA = A + (size_t)m0 * K;
    const u16* gB = Bt + (size_t)n0 * K;

    f32x4 acc[8][3];
    f32x4 z = {0.f, 0.f, 0.f, 0.f};
#pragma unroll
    for (int m = 0; m < 8; m++)
#pragma unroll
        for (int n = 0; n < 3; n++) acc[m][n] = z;

    stage_rows(gA, ldsA[0], 0, 0, K, t);
    stage_rows(gA, ldsA[0], 128, 0, K, t);
    stage_rows(gB, ldsB[0], 0, 0, K, t);
    stage_rows(gB, ldsB[0], 64, 0, K, t);
    stage_rows(gB, ldsB[0], 128, 0, K, t);
    stage_rows(gA, ldsA[0], 64, 0, K, t);
    stage_rows(gA, ldsA[0], 192, 0, K, t);

    const int KT = K >> 6;
    for (int kt = 0; kt < KT; ++kt) {
        const int c = kt & 1;
        const int kn = (kt + 1 < KT) ? (kt + 1) * 64 : kt * 64;
        const u16* lAc = ldsA[c];
        const u16* lBc = ldsB[c];
        u16* lAn = ldsA[c ^ 1];
        u16* lBn = ldsB[c ^ 1];

        bf16x8 aF[4][2], bF[3][2];

        asm volatile("s_waitcnt vmcnt(2)" ::: "memory");
        __builtin_amdgcn_s_barrier();
#pragma unroll
        for (int mi = 0; mi < 4; mi++)
#pragma unroll
            for (int kc = 0; kc < 2; kc++)
                aF[mi][kc] = lds_ld(lAc, wr * 128 + mi * 16 + l15, kc, hl);
#pragma unroll
        for (int n = 0; n < 3; n++)
#pragma unroll
            for (int kc = 0; kc < 2; kc++)
                bF[n][kc] = lds_ld(lBc, wc * 48 + n * 16 + l15, kc, hl);
        stage_rows(gA, lAn, 0, kn, K, t);
        stage_rows(gA, lAn, 128, kn, K, t);
        stage_rows(gB, lBn, 0, kn, K, t);
        __builtin_amdgcn_s_setprio(1);
#pragma unroll
        for (int mi = 0; mi < 4; mi++)
#pragma unroll
            for (int n = 0; n < 3; n++)
#pragma unroll
                for (int kc = 0; kc < 2; kc++)
                    acc[mi][n] = __builtin_amdgcn_mfma_f32_16x16x32_bf16(aF[mi][kc], bF[n][kc], acc[mi][n], 0, 0, 0);
        __builtin_amdgcn_s_setprio(0);

        asm volatile("s_waitcnt vmcnt(3)" ::: "memory");
        __builtin_amdgcn_s_barrier();
#pragma unroll
        for (int mi = 0; mi < 4; mi++)
#pragma unroll
            for (int kc = 0; kc < 2; kc++)
                aF[mi][kc] = lds_ld(lAc, wr * 128 + 64 + mi * 16 + l15, kc, hl);
        stage_rows(gB, lBn, 64, kn, K, t);
        stage_rows(gB, lBn, 128, kn, K, t);
        stage_rows(gA, lAn, 64, kn, K, t);
        stage_rows(gA, lAn, 192, kn, K, t);
        __builtin_amdgcn_s_setprio(1);
#pragma unroll
        for (int mi = 0; mi < 4; mi++)
#pragma unroll
            for (int n = 0; n < 3; n++)
#pragma unroll
                for (int kc = 0; kc < 2; kc++)
                    acc[4 + mi][n] = __builtin_amdgcn_mfma_f32_16x16x32_bf16(aF[mi][kc], bF[n][kc], acc[4 + mi][n], 0, 0, 0);
        __builtin_amdgcn_s_setprio(0);
    }

#pragma unroll
    for (int m = 0; m < 8; m++)
#pragma unroll
        for (int n = 0; n < 3; n++)
#pragma unroll
            for (int r = 0; r < 4; r++) {
                int row = m0 + wr * 128 + m * 16 + hl * 4 + r;
                int col = n0 + wc * 48 + n * 16 + l15;
                C[(size_t)row * N + col] = f2bf(acc[m][n][r]);
            }
}

// ================= proj GEMM: 128x256 tiles, 256 blocks (1/CU), f32 out =================
__global__ __launch_bounds__(512, 2) void gemm_proj(const u16* __restrict__ A, const u16* __restrict__ Bt,
                                                    float* __restrict__ C, int M, int N, int K) {
    __shared__ alignas(16) u16 ldsA[2][128 * 64];
    __shared__ alignas(16) u16 ldsB[2][256 * 64];
    const int t = threadIdx.x, wave = t >> 6, lane = t & 63;
    const int l15 = lane & 15, hl = lane >> 4;
    const int wr = wave >> 2, wc = wave & 3;

    const int f = blockIdx.x;
    const int swz = (f & 7) * 32 + (f >> 3);
    const int bx = swz & 31, by = swz >> 5;
    const int m0 = bx * 128, n0 = by * 256;

    const u16* gA = A + (size_t)m0 * K;
    const u16* gB = Bt + (size_t)n0 * K;

    f32x4 acc[4][4];
    f32x4 z = {0.f, 0.f, 0.f, 0.f};
#pragma unroll
    for (int m = 0; m < 4; m++)
#pragma unroll
        for (int n = 0; n < 4; n++) acc[m][n] = z;

    stage_rows(gA, ldsA[0], 0, 0, K, t);
    stage_rows(gA, ldsA[0], 64, 0, K, t);
    stage_half256(gB, ldsB[0], 0, 0, 0, K, t);
    stage_half256(gB, ldsB[0], 0, 1, 0, K, t);
    stage_half256(gB, ldsB[0], 1, 0, 0, K, t);
    stage_half256(gB, ldsB[0], 1, 1, 0, K, t);

    const int KT = K >> 6;
    for (int kt = 0; kt < KT; ++kt) {
        const int c = kt & 1;
        const int kn = (kt + 1 < KT) ? (kt + 1) * 64 : kt * 64;
        const u16* lAc = ldsA[c];
        const u16* lBc = ldsB[c];
        u16* lAn = ldsA[c ^ 1];
        u16* lBn = ldsB[c ^ 1];

        bf16x8 aF[4][2], bF[2][2];

        asm volatile("s_waitcnt vmcnt(2)" ::: "memory");
        __builtin_amdgcn_s_barrier();
#pragma unroll
        for (int mi = 0; mi < 4; mi++)
#pragma unroll
            for (int kc = 0; kc < 2; kc++)
                aF[mi][kc] = lds_ld(lAc, wr * 64 + mi * 16 + l15, kc, hl);
#pragma unroll
        for (int n = 0; n < 2; n++)
#pragma unroll
            for (int kc = 0; kc < 2; kc++)
                bF[n][kc] = lds_ld(lBc, wc * 64 + n * 16 + l15, kc, hl);
        stage_rows(gA, lAn, 0, kn, K, t);
        stage_rows(gA, lAn, 64, kn, K, t);
        stage_half256(gB, lBn, 0, 0, kn, K, t);
        stage_half256(gB, lBn, 0, 1, kn, K, t);
        __builtin_amdgcn_s_setprio(1);
#pragma unroll
        for (int mi = 0; mi < 4; mi++)
#pragma unroll
            for (int n = 0; n < 2; n++)
#pragma unroll
                for (int kc = 0; kc < 2; kc++)
                    acc[mi][n] = __builtin_amdgcn_mfma_f32_16x16x32_bf16(aF[mi][kc], bF[n][kc], acc[mi][n], 0, 0, 0);
        __builtin_amdgcn_s_setprio(0);

        asm volatile("s_waitcnt vmcnt(4)" ::: "memory");
        __builtin_amdgcn_s_barrier();
#pragma unroll
        for (int n = 0; n < 2; n++)
#pragma unroll
            for (int kc = 0; kc < 2; kc++)
                bF[n][kc] = lds_ld(lBc, wc * 64 + 32 + n * 16 + l15, kc, hl);
        stage_half256(gB, lBn, 1, 0, kn, K, t);
        stage_half256(gB, lBn, 1, 1, kn, K, t);
        __builtin_amdgcn_s_setprio(1);
#pragma unroll
        for (int mi = 0; mi < 4; mi++)
#pragma unroll
            for (int n = 0; n < 2; n++)
#pragma unroll
                for (int kc = 0; kc < 2; kc++)
                    acc[mi][2 + n] = __builtin_amdgcn_mfma_f32_16x16x32_bf16(aF[mi][kc], bF[n][kc], acc[mi][2 + n], 0, 0, 0);
        __builtin_amdgcn_s_setprio(0);
    }

#pragma unroll
    for (int m = 0; m < 4; m++)
#pragma unroll
        for (int n = 0; n < 4; n++)
#pragma unroll
            for (int r = 0; r < 4; r++) {
                int row = m0 + wr * 64 + m * 16 + hl * 4 + r;
                int col = n0 + wc * 64 + n * 16 + l15;
                C[(size_t)row * N + col] = acc[m][n][r];
            }
}

// ---------------- fused RoPE (vectorized x4, in place) + V transpose ----------------
__global__ void rope_vtrans(u16* __restrict__ qkv, u16* __restrict__ vt,
                            const int* __restrict__ pos) {
    __shared__ alignas(16) u16 sT[64 * 72];
    const int t = threadIdx.x;
    if (blockIdx.x < 512) {
        const int f = blockIdx.x;
        const int t0 = (f & 31) * 64;
        const int d0 = ((f >> 5) & 1) * 64;
        const int kh = (f >> 6) & 3, b = f >> 8;
#pragma unroll
        for (int i = 0; i < 2; i++) {
            int tr = i * 32 + (t >> 3), dc = (t & 7) * 8;
            *(u16x8*)&sT[tr * 72 + dc] =
                *(const u16x8*)&qkv[(size_t)(b * T_SEQ + t0 + tr) * 3072 + 2560 + kh * 128 + d0 + dc];
        }
        __syncthreads();
#pragma unroll
        for (int i = 0; i < 2; i++) {
            int dr = i * 32 + (t >> 3), tc = (t & 7) * 8;
            u16x8 v;
#pragma unroll
            for (int j = 0; j < 8; j++) v[j] = sT[(tc + j) * 72 + dr];
            *(u16x8*)&vt[((size_t)(b * 4 + kh) * 128 + d0 + dr) * 2048 + t0 + tc] = v;
        }
    } else {
        int tid = (blockIdx.x - 512) * 256 + t;
        int j4 = tid & 15;
        int rest = tid >> 4;
        int slice = rest % 20;
        int row = rest / 20;
        if (row >= 2 * T_SEQ) return;
        float tpos = (float)((row % T_SEQ) + pos[0]);
        int base = (slice < 16) ? slice * 128 : 2048 + (slice - 16) * 128;
        u16* p = qkv + (size_t)row * 3072 + base + j4 * 4;
        u16x4 lo = *(const u16x4*)p;
        u16x4 hi = *(const u16x4*)(p + 64);
        const float c0 = 0.20762050593045702f;   // log2(10000)/64
        u16x4 olo, ohi;
#pragma unroll
        for (int e = 0; e < 4; e++) {
            int i = (j4 * 4 + e) >> 1;
            float fA = tpos * exp2f(-(float)i * c0);
            float fB = tpos * exp2f(-(float)(32 + i) * c0);
            float x1 = bf2f(lo[e]), x2 = bf2f(hi[e]);
            olo[e] = f2bf(x1 * cosf(fA) - x2 * sinf(fA));
            ohi[e] = f2bf(x2 * cosf(fB) + x1 * sinf(fB));
        }
        *(u16x4*)p = olo;
        *(u16x4*)(p + 64) = ohi;
    }
}

// ---------------- causal GQA flash attention: 8 waves x 16 q-rows ----------------
// R13/R16-proven structure: 3 barriers, counted vmcnt (4)/(2), K dbuf + V sbuf,
// interior-tile mask fast path, deferred max, ones-MFMA row sums.
__global__ __launch_bounds__(512, 4) void attn(const u16* __restrict__ qkv,
                                               const u16* __restrict__ vt,
                                               u16* __restrict__ out) {
    __shared__ alignas(16) u16 sK[2][8192];       // [64][128] XOR-swizzled content
    __shared__ alignas(16) u16 sV[8192];          // [128][64] XOR-swizzled content
    __shared__ alignas(16) __bf16 sP[128 * 72];
    const int t = threadIdx.x, wave = t >> 6, lane = t & 63;
    const int l15 = lane & 15, hl = lane >> 4;

    const int f = blockIdx.x;
    const int sel = f >> 8, u = f & 255;
    const int bkh = u & 7, b = bkh >> 2, kh = bkh & 3;
    const int h = kh * 4 + ((u >> 3) & 3);
    const int j = u >> 5;
    const int a = sel ? (15 - j) : j;
    const int q0 = a * 128;
    const int nt = 2 * a + 2;

    const float sc = 0.08838834764831845f;

    bf16x8 qf[4];
#pragma unroll
    for (int c = 0; c < 4; c++) {
        const u16* qp = qkv + (size_t)(b * T_SEQ + q0 + wave * 16 + l15) * 3072
                        + h * 128 + c * 32 + hl * 8;
        u16x8 raw = *(const u16x8*)qp;
        u16x8 sv_;
#pragma unroll
        for (int e = 0; e < 8; e++) sv_[e] = f2bf(bf2f(raw[e]) * sc);
        qf[c] = *(bf16x8*)&sv_;
    }

    u16x8 onesu;
#pragma unroll
    for (int e = 0; e < 8; e++) onesu[e] = 0x3F80;
    const bf16x8 onesf = *(bf16x8*)&onesu;

    float mrow[4];
    f32x4 o[8];
    f32x4 osum;
    f32x4 z = {0.f, 0.f, 0.f, 0.f};
#pragma unroll
    for (int r = 0; r < 4; r++) mrow[r] = -1e30f;
    osum = z;
#pragma unroll
    for (int n8 = 0; n8 < 8; n8++) o[n8] = z;

    asm volatile("s_waitcnt vmcnt(0)" ::: "memory");

    const u16* kgbase = qkv + (size_t)(b * T_SEQ) * 3072 + 2048 + kh * 128;
    const u16* vgbase = vt + (size_t)(b * 4 + kh) * 128 * 2048;

#pragma unroll
    for (int p = 0; p < 2; p++) {
        int i = p * 512 + t;
        int row = i >> 4, c = i & 15;
        gload_lds16(kgbase + (size_t)row * 3072 + ((c ^ (row & 7)) * 8), (u16*)sK[0] + i * 8);
    }

    int cur = 0;
    for (int it = 0; it < nt; ++it) {
        const int kv0 = it * 64;
        const int kvn = (it + 1 < nt) ? kv0 + 64 : kv0;
#pragma unroll
        for (int p = 0; p < 2; p++) {
            int i = p * 512 + t;
            int row = i >> 3, c = i & 7;
            gload_lds16(vgbase + (size_t)row * 2048 + kv0 + ((c ^ (row & 7)) * 8), sV + i * 8);
        }
#pragma unroll
        for (int p = 0; p < 2; p++) {
            int i = p * 512 + t;
            int row = i >> 4, c = i & 15;
            gload_lds16(kgbase + (size_t)(kvn + row) * 3072 + ((c ^ (row & 7)) * 8),
                        (u16*)sK[cur ^ 1] + i * 8);
        }
        asm volatile("s_waitcnt vmcnt(4)" ::: "memory");   // K(t) landed
        __builtin_amdgcn_s_barrier();

        // S = Q K^T  (16 rows x 64 cols per wave)
        f32x4 sA[4];
#pragma unroll
        for (int n = 0; n < 4; n++) sA[n] = z;
#pragma unroll
        for (int n = 0; n < 4; n++)
#pragma unroll
            for (int c = 0; c < 4; c++) {
                int row = n * 16 + l15;
                bf16x8 kf = *(const bf16x8*)&sK[cur][row * 128 + (((c * 4 + hl) ^ (row & 7)) * 8)];
                sA[n] = __builtin_amdgcn_mfma_f32_16x16x32_bf16(qf[c], kf, sA[n], 0, 0, 0);
            }

        // online softmax: interior tiles skip causal mask entirely (wave-uniform)
        const bool full = (kv0 + 63 <= q0 + wave * 16);
        if (full) {
#pragma unroll
            for (int r = 0; r < 4; r++) {
                float pmax = fmaxf(fmaxf(sA[0][r], sA[1][r]), fmaxf(sA[2][r], sA[3][r]));
                if (__builtin_expect(__any(pmax > mrow[r] + 8.f), 0)) {
                    float mx = pmax;
#pragma unroll
                    for (int off = 1; off < 16; off <<= 1) mx = fmaxf(mx, __shfl_xor(mx, off));
                    float mnew = fmaxf(mrow[r], mx);
                    float alpha = __expf(mrow[r] - mnew);
                    mrow[r] = mnew;
#pragma unroll
                    for (int n8 = 0; n8 < 8; n8++) o[n8][r] *= alpha;
                    osum[r] *= alpha;
                }
#pragma unroll
                for (int n = 0; n < 4; n++)
                    sP[(wave * 16 + hl * 4 + r) * 72 + n * 16 + l15] =
                        (__bf16)__expf(sA[n][r] - mrow[r]);
            }
        } else {
#pragma unroll
            for (int r = 0; r < 4; r++) {
                const int grow = q0 + wave * 16 + hl * 4 + r;
                float mv[4];
#pragma unroll
                for (int n = 0; n < 4; n++)
                    mv[n] = (kv0 + n * 16 + l15 <= grow) ? sA[n][r] : -1e30f;
                float pmax = fmaxf(fmaxf(mv[0], mv[1]), fmaxf(mv[2], mv[3]));
                if (__builtin_expect(__any(pmax > mrow[r] + 8.f), 0)) {
                    float mx = pmax;
#pragma unroll
                    for (int off = 1; off < 16; off <<= 1) mx = fmaxf(mx, __shfl_xor(mx, off));
                    float mnew = fmaxf(mrow[r], mx);
                    float alpha = __expf(mrow[r] - mnew);
                    mrow[r] = mnew;
#pragma unroll
                    for (int n8 = 0; n8 < 8; n8++) o[n8][r] *= alpha;
                    osum[r] *= alpha;
                }
#pragma unroll
                for (int n = 0; n < 4; n++)
                    sP[(wave * 16 + hl * 4 + r) * 72 + n * 16 + l15] =
                        (__bf16)__expf(mv[n] - mrow[r]);
            }
        }

        asm volatile("s_waitcnt vmcnt(2)" ::: "memory");   // V(t) landed
        __builtin_amdgcn_s_barrier();

        bf16x8 pa[2];
#pragma unroll
        for (int k2 = 0; k2 < 2; k2++)
            pa[k2] = *(const bf16x8*)&sP[(wave * 16 + l15) * 72 + k2 * 32 + hl * 8];
#pragma unroll
        for (int k2 = 0; k2 < 2; k2++)
            osum = __builtin_amdgcn_mfma_f32_16x16x32_bf16(pa[k2], onesf, osum, 0, 0, 0);
#pragma unroll
        for (int n8 = 0; n8 < 8; n8++)
#pragma unroll
            for (int k2 = 0; k2 < 2; k2++) {
                int d = n8 * 16 + l15;
                bf16x8 vf = *(const bf16x8*)&sV[d * 64 + (((k2 * 4 + hl) ^ (d & 7)) * 8)];
                o[n8] = __builtin_amdgcn_mfma_f32_16x16x32_bf16(pa[k2], vf, o[n8], 0, 0, 0);
            }
        __builtin_amdgcn_s_barrier();
        cur ^= 1;
    }

#pragma unroll
    for (int r = 0; r < 4; r++) {
        float inv = 1.f / osum[r];
        int orow = b * T_SEQ + q0 + wave * 16 + hl * 4 + r;
#pragma unroll
        for (int n8 = 0; n8 < 8; n8++)
            out[(size_t)orow * 2048 + h * 128 + n8 * 16 + l15] = f2bf(o[n8][r] * inv);
    }
}

extern "C" void kernel_launch(void* const* d_in, const int* in_sizes, int n_in,
                              void* d_out, int out_size, void* d_ws, size_t ws_size,
                              hipStream_t stream) {
    const float* x  = (const float*)d_in[0];
    const float* Wq = (const float*)d_in[1];
    const float* Wk = (const float*)d_in[2];
    const float* Wv = (const float*)d_in[3];
    const float* Wp = (const float*)d_in[4];
    const int*   pos = (const int*)d_in[5];

    char* ws = (char*)d_ws;
    u16* xbf   = (u16*)(ws);                        // 4096*2048 bf16
    u16* WtQKV = (u16*)(ws + 16777216);             // 3072*2048 bf16
    u16* WtP   = (u16*)(ws + 29360128);             // 2048*2048 bf16
    u16* QKV   = (u16*)(ws + 37748736);             // 4096*3072 bf16
    u16* Vt    = (u16*)(ws + 62914560);             // 2*4*128*2048 bf16
    u16* AO    = (u16*)(ws + 67108864);             // 4096*2048 bf16

    prep_all<<<4096 + 2560, 256, 0, stream>>>(x, xbf, Wq, Wk, Wv, Wp, WtQKV, WtP);
    gemm_qkv<<<256, 512, 0, stream>>>(xbf, WtQKV, QKV, 4096, 3072, 2048);
    rope_vtrans<<<512 + 5120, 256, 0, stream>>>(QKV, Vt, pos);
    attn<<<512, 512, 0, stream>>>(QKV, Vt, AO);
    gemm_proj<<<256, 512, 0, stream>>>(AO, WtP, (float*)d_out, 4096, 2048, 2048);
}

// Round 20
// 182.561 us; speedup vs baseline: 1.0590x; 1.0030x over previous
//
#include <hip/hip_runtime.h>
#include <hip/hip_bf16.h>
#include <stdint.h>

typedef unsigned short u16;
typedef float f32x4 __attribute__((ext_vector_type(4)));
typedef __bf16 bf16x8 __attribute__((ext_vector_type(8)));
typedef unsigned short u16x8 __attribute__((ext_vector_type(8)));
typedef unsigned short u16x4 __attribute__((ext_vector_type(4)));
typedef float f32x4v __attribute__((ext_vector_type(4)));

#define T_SEQ 2048

__device__ __forceinline__ u16 f2bf(float f) {
    unsigned int u = __float_as_uint(f);
    unsigned int r = (u + 0x7fffu + ((u >> 16) & 1u)) >> 16;
    return (u16)r;
}
__device__ __forceinline__ float bf2f(u16 b) {
    return __uint_as_float(((unsigned int)b) << 16);
}

__device__ __forceinline__ void gload_lds16(const void* g, void* l) {
    __builtin_amdgcn_global_load_lds(
        (__attribute__((address_space(1))) void*)(g),
        (__attribute__((address_space(3))) void*)(l), 16, 0, 0);
}

// ---------- fused preprocessing: x cast (blocks 0..4095) + W transposes ----------
__global__ void prep_all(const float* __restrict__ x, u16* __restrict__ xbf,
                         const float* __restrict__ Wq, const float* __restrict__ Wk,
                         const float* __restrict__ Wv, const float* __restrict__ Wp,
                         u16* __restrict__ WtQKV, u16* __restrict__ WtP) {
    __shared__ alignas(16) float sW[64 * 68];
    const int t = threadIdx.x;
    const int bid = blockIdx.x;
    if (bid < 4096) {
        int i = bid * 256 + t;
        const f32x4v* p = (const f32x4v*)(x + (size_t)i * 8);
        f32x4v a = p[0], bb = p[1];
        u16x8 v;
        v[0]=f2bf(a.x); v[1]=f2bf(a.y); v[2]=f2bf(a.z); v[3]=f2bf(a.w);
        v[4]=f2bf(bb.x); v[5]=f2bf(bb.y); v[6]=f2bf(bb.z); v[7]=f2bf(bb.w);
        *(u16x8*)(xbf + (size_t)i * 8) = v;
        return;
    }
    const int rem = bid - 4096;
    const int y = rem >> 5;
    const float* W; u16* dst; int N; int n0;
    if (y < 32)      { W = Wq; dst = WtQKV;                       N = 2048; n0 = y * 64; }
    else if (y < 40) { W = Wk; dst = WtQKV + (size_t)2048 * 2048; N = 512;  n0 = (y - 32) * 64; }
    else if (y < 48) { W = Wv; dst = WtQKV + (size_t)2560 * 2048; N = 512;  n0 = (y - 40) * 64; }
    else             { W = Wp; dst = WtP;                         N = 2048; n0 = (y - 48) * 64; }
    const int k0 = (rem & 31) * 64;
#pragma unroll
    for (int i = 0; i < 4; i++) {
        int kr = i * 16 + (t >> 4), nc = (t & 15) * 4;
        *(f32x4v*)&sW[kr * 68 + nc] = *(const f32x4v*)&W[(size_t)(k0 + kr) * N + n0 + nc];
    }
    __syncthreads();
#pragma unroll
    for (int i = 0; i < 2; i++) {
        int nr = i * 32 + (t >> 3), kc = (t & 7) * 8;
        u16x8 v;
#pragma unroll
        for (int j = 0; j < 8; j++) v[j] = f2bf(sW[(kc + j) * 68 + nr]);
        *(u16x8*)&dst[(size_t)(n0 + nr) * 2048 + k0 + kc] = v;
    }
}

// ======== shared staging helpers (XOR-swizzled content, linear LDS) ========
__device__ __forceinline__ void stage_rows(const u16* g, u16* lds, int R, int kcol0, int K, int t) {
    int row = R + (t >> 3);
    int u = t & 7;
    gload_lds16(g + (size_t)row * K + kcol0 + ((u ^ (row & 7)) * 8), lds + row * 64 + u * 8);
}
__device__ __forceinline__ void stage_half256(const u16* g, u16* lds, int half, int j, int kcol0, int K, int t) {
    int idx = j * 512 + t;
    int group = idx >> 8;
    int r32 = (idx >> 3) & 31;
    int row = group * 64 + half * 32 + r32;
    int u = idx & 7;
    gload_lds16(g + (size_t)row * K + kcol0 + ((u ^ (row & 7)) * 8), lds + row * 64 + u * 8);
}
__device__ __forceinline__ bf16x8 lds_ld(const u16* lds, int row, int kc, int hl) {
    return *(const bf16x8*)&lds[row * 64 + (((kc * 4 + hl) ^ (row & 7)) * 8)];
}

// ================= QKV GEMM: 256x192 tiles, 256 blocks (1/CU) =================
__global__ __launch_bounds__(512, 2) void gemm_qkv(const u16* __restrict__ A, const u16* __restrict__ Bt,
                                                   u16* __restrict__ C, int M, int N, int K) {
    __shared__ alignas(16) u16 ldsA[2][256 * 64];
    __shared__ alignas(16) u16 ldsB[2][192 * 64];
    const int t = threadIdx.x, wave = t >> 6, lane = t & 63;
    const int l15 = lane & 15, hl = lane >> 4;
    const int wr = wave >> 2, wc = wave & 3;

    const int f = blockIdx.x;
    const int swz = (f & 7) * 32 + (f >> 3);
    const int bx = swz & 15, by = swz >> 4;
    const int m0 = bx * 256, n0 = by * 192;

    const u16* gA = A + (size_t)m0 * K;
    const u16* gB = Bt + (size_t)n0 * K;

    f32x4 acc[8][3];
    f32x4 z = {0.f, 0.f, 0.f, 0.f};
#pragma unroll
    for (int m = 0; m < 8; m++)
#pragma unroll
        for (int n = 0; n < 3; n++) acc[m][n] = z;

    stage_rows(gA, ldsA[0], 0, 0, K, t);
    stage_rows(gA, ldsA[0], 128, 0, K, t);
    stage_rows(gB, ldsB[0], 0, 0, K, t);
    stage_rows(gB, ldsB[0], 64, 0, K, t);
    stage_rows(gB, ldsB[0], 128, 0, K, t);
    stage_rows(gA, ldsA[0], 64, 0, K, t);
    stage_rows(gA, ldsA[0], 192, 0, K, t);

    const int KT = K >> 6;
    for (int kt = 0; kt < KT; ++kt) {
        const int c = kt & 1;
        const int kn = (kt + 1 < KT) ? (kt + 1) * 64 : kt * 64;
        const u16* lAc = ldsA[c];
        const u16* lBc = ldsB[c];
        u16* lAn = ldsA[c ^ 1];
        u16* lBn = ldsB[c ^ 1];

        bf16x8 aF[4][2], bF[3][2];

        asm volatile("s_waitcnt vmcnt(2)" ::: "memory");
        __builtin_amdgcn_s_barrier();
#pragma unroll
        for (int mi = 0; mi < 4; mi++)
#pragma unroll
            for (int kc = 0; kc < 2; kc++)
                aF[mi][kc] = lds_ld(lAc, wr * 128 + mi * 16 + l15, kc, hl);
#pragma unroll
        for (int n = 0; n < 3; n++)
#pragma unroll
            for (int kc = 0; kc < 2; kc++)
                bF[n][kc] = lds_ld(lBc, wc * 48 + n * 16 + l15, kc, hl);
        stage_rows(gA, lAn, 0, kn, K, t);
        stage_rows(gA, lAn, 128, kn, K, t);
        stage_rows(gB, lBn, 0, kn, K, t);
        __builtin_amdgcn_s_setprio(1);
#pragma unroll
        for (int mi = 0; mi < 4; mi++)
#pragma unroll
            for (int n = 0; n < 3; n++)
#pragma unroll
                for (int kc = 0; kc < 2; kc++)
                    acc[mi][n] = __builtin_amdgcn_mfma_f32_16x16x32_bf16(aF[mi][kc], bF[n][kc], acc[mi][n], 0, 0, 0);
        __builtin_amdgcn_s_setprio(0);

        asm volatile("s_waitcnt vmcnt(3)" ::: "memory");
        __builtin_amdgcn_s_barrier();
#pragma unroll
        for (int mi = 0; mi < 4; mi++)
#pragma unroll
            for (int kc = 0; kc < 2; kc++)
                aF[mi][kc] = lds_ld(lAc, wr * 128 + 64 + mi * 16 + l15, kc, hl);
        stage_rows(gB, lBn, 64, kn, K, t);
        stage_rows(gB, lBn, 128, kn, K, t);
        stage_rows(gA, lAn, 64, kn, K, t);
        stage_rows(gA, lAn, 192, kn, K, t);
        __builtin_amdgcn_s_setprio(1);
#pragma unroll
        for (int mi = 0; mi < 4; mi++)
#pragma unroll
            for (int n = 0; n < 3; n++)
#pragma unroll
                for (int kc = 0; kc < 2; kc++)
                    acc[4 + mi][n] = __builtin_amdgcn_mfma_f32_16x16x32_bf16(aF[mi][kc], bF[n][kc], acc[4 + mi][n], 0, 0, 0);
        __builtin_amdgcn_s_setprio(0);
    }

#pragma unroll
    for (int m = 0; m < 8; m++)
#pragma unroll
        for (int n = 0; n < 3; n++)
#pragma unroll
            for (int r = 0; r < 4; r++) {
                int row = m0 + wr * 128 + m * 16 + hl * 4 + r;
                int col = n0 + wc * 48 + n * 16 + l15;
                C[(size_t)row * N + col] = f2bf(acc[m][n][r]);
            }
}

// ================= proj GEMM: 128x256 tiles, 256 blocks (1/CU), f32 out =================
__global__ __launch_bounds__(512, 2) void gemm_proj(const u16* __restrict__ A, const u16* __restrict__ Bt,
                                                    float* __restrict__ C, int M, int N, int K) {
    __shared__ alignas(16) u16 ldsA[2][128 * 64];
    __shared__ alignas(16) u16 ldsB[2][256 * 64];
    const int t = threadIdx.x, wave = t >> 6, lane = t & 63;
    const int l15 = lane & 15, hl = lane >> 4;
    const int wr = wave >> 2, wc = wave & 3;

    const int f = blockIdx.x;
    const int swz = (f & 7) * 32 + (f >> 3);
    const int bx = swz & 31, by = swz >> 5;
    const int m0 = bx * 128, n0 = by * 256;

    const u16* gA = A + (size_t)m0 * K;
    const u16* gB = Bt + (size_t)n0 * K;

    f32x4 acc[4][4];
    f32x4 z = {0.f, 0.f, 0.f, 0.f};
#pragma unroll
    for (int m = 0; m < 4; m++)
#pragma unroll
        for (int n = 0; n < 4; n++) acc[m][n] = z;

    stage_rows(gA, ldsA[0], 0, 0, K, t);
    stage_rows(gA, ldsA[0], 64, 0, K, t);
    stage_half256(gB, ldsB[0], 0, 0, 0, K, t);
    stage_half256(gB, ldsB[0], 0, 1, 0, K, t);
    stage_half256(gB, ldsB[0], 1, 0, 0, K, t);
    stage_half256(gB, ldsB[0], 1, 1, 0, K, t);

    const int KT = K >> 6;
    for (int kt = 0; kt < KT; ++kt) {
        const int c = kt & 1;
        const int kn = (kt + 1 < KT) ? (kt + 1) * 64 : kt * 64;
        const u16* lAc = ldsA[c];
        const u16* lBc = ldsB[c];
        u16* lAn = ldsA[c ^ 1];
        u16* lBn = ldsB[c ^ 1];

        bf16x8 aF[4][2], bF[2][2];

        asm volatile("s_waitcnt vmcnt(2)" ::: "memory");
        __builtin_amdgcn_s_barrier();
#pragma unroll
        for (int mi = 0; mi < 4; mi++)
#pragma unroll
            for (int kc = 0; kc < 2; kc++)
                aF[mi][kc] = lds_ld(lAc, wr * 64 + mi * 16 + l15, kc, hl);
#pragma unroll
        for (int n = 0; n < 2; n++)
#pragma unroll
            for (int kc = 0; kc < 2; kc++)
                bF[n][kc] = lds_ld(lBc, wc * 64 + n * 16 + l15, kc, hl);
        stage_rows(gA, lAn, 0, kn, K, t);
        stage_rows(gA, lAn, 64, kn, K, t);
        stage_half256(gB, lBn, 0, 0, kn, K, t);
        stage_half256(gB, lBn, 0, 1, kn, K, t);
        __builtin_amdgcn_s_setprio(1);
#pragma unroll
        for (int mi = 0; mi < 4; mi++)
#pragma unroll
            for (int n = 0; n < 2; n++)
#pragma unroll
                for (int kc = 0; kc < 2; kc++)
                    acc[mi][n] = __builtin_amdgcn_mfma_f32_16x16x32_bf16(aF[mi][kc], bF[n][kc], acc[mi][n], 0, 0, 0);
        __builtin_amdgcn_s_setprio(0);

        asm volatile("s_waitcnt vmcnt(4)" ::: "memory");
        __builtin_amdgcn_s_barrier();
#pragma unroll
        for (int n = 0; n < 2; n++)
#pragma unroll
            for (int kc = 0; kc < 2; kc++)
                bF[n][kc] = lds_ld(lBc, wc * 64 + 32 + n * 16 + l15, kc, hl);
        stage_half256(gB, lBn, 1, 0, kn, K, t);
        stage_half256(gB, lBn, 1, 1, kn, K, t);
        __builtin_amdgcn_s_setprio(1);
#pragma unroll
        for (int mi = 0; mi < 4; mi++)
#pragma unroll
            for (int n = 0; n < 2; n++)
#pragma unroll
                for (int kc = 0; kc < 2; kc++)
                    acc[mi][2 + n] = __builtin_amdgcn_mfma_f32_16x16x32_bf16(aF[mi][kc], bF[n][kc], acc[mi][2 + n], 0, 0, 0);
        __builtin_amdgcn_s_setprio(0);
    }

#pragma unroll
    for (int m = 0; m < 4; m++)
#pragma unroll
        for (int n = 0; n < 4; n++)
#pragma unroll
            for (int r = 0; r < 4; r++) {
                int row = m0 + wr * 64 + m * 16 + hl * 4 + r;
                int col = n0 + wc * 64 + n * 16 + l15;
                C[(size_t)row * N + col] = acc[m][n][r];
            }
}

// ---------------- fused RoPE (K heads only; Q roped in attn) + V transpose ----------------
__global__ void rope_vtrans(u16* __restrict__ qkv, u16* __restrict__ vt,
                            const int* __restrict__ pos) {
    __shared__ alignas(16) u16 sT[64 * 72];
    const int t = threadIdx.x;
    if (blockIdx.x < 512) {
        const int f = blockIdx.x;
        const int t0 = (f & 31) * 64;
        const int d0 = ((f >> 5) & 1) * 64;
        const int kh = (f >> 6) & 3, b = f >> 8;
#pragma unroll
        for (int i = 0; i < 2; i++) {
            int tr = i * 32 + (t >> 3), dc = (t & 7) * 8;
            *(u16x8*)&sT[tr * 72 + dc] =
                *(const u16x8*)&qkv[(size_t)(b * T_SEQ + t0 + tr) * 3072 + 2560 + kh * 128 + d0 + dc];
        }
        __syncthreads();
#pragma unroll
        for (int i = 0; i < 2; i++) {
            int dr = i * 32 + (t >> 3), tc = (t & 7) * 8;
            u16x8 v;
#pragma unroll
            for (int j = 0; j < 8; j++) v[j] = sT[(tc + j) * 72 + dr];
            *(u16x8*)&vt[((size_t)(b * 4 + kh) * 128 + d0 + dr) * 2048 + t0 + tc] = v;
        }
    } else {
        // rope on K heads only: 4 slices (cols 2048..2560), 16 threads per (row, slice)
        int tid = (blockIdx.x - 512) * 256 + t;
        int j4 = tid & 15;
        int rest = tid >> 4;
        int slice = rest & 3;
        int row = rest >> 2;
        if (row >= 2 * T_SEQ) return;
        float tpos = (float)((row % T_SEQ) + pos[0]);
        int base = 2048 + slice * 128;
        u16* p = qkv + (size_t)row * 3072 + base + j4 * 4;
        u16x4 lo = *(const u16x4*)p;
        u16x4 hi = *(const u16x4*)(p + 64);
        const float c0 = 0.20762050593045702f;   // log2(10000)/64
        u16x4 olo, ohi;
#pragma unroll
        for (int e = 0; e < 4; e++) {
            int i = (j4 * 4 + e) >> 1;
            float fA = tpos * exp2f(-(float)i * c0);
            float fB = tpos * exp2f(-(float)(32 + i) * c0);
            float x1 = bf2f(lo[e]), x2 = bf2f(hi[e]);
            olo[e] = f2bf(x1 * cosf(fA) - x2 * sinf(fA));
            ohi[e] = f2bf(x2 * cosf(fB) + x1 * sinf(fB));
        }
        *(u16x4*)p = olo;
        *(u16x4*)(p + 64) = ohi;
    }
}

// ---------------- causal GQA flash attention: 8 waves x 16 q-rows ----------------
// R16-proven structure; Q-RoPE applied in registers at load (pairs are lane-local:
// d = c*32+hl*8+e pairs with d+64 at c+2, same lane/e).
__global__ __launch_bounds__(512, 4) void attn(const u16* __restrict__ qkv,
                                               const u16* __restrict__ vt,
                                               u16* __restrict__ out,
                                               const int* __restrict__ pos) {
    __shared__ alignas(16) u16 sK[2][8192];       // [64][128] XOR-swizzled content
    __shared__ alignas(16) u16 sV[8192];          // [128][64] XOR-swizzled content
    __shared__ alignas(16) __bf16 sP[128 * 72];
    const int t = threadIdx.x, wave = t >> 6, lane = t & 63;
    const int l15 = lane & 15, hl = lane >> 4;

    const int f = blockIdx.x;
    const int sel = f >> 8, u = f & 255;
    const int bkh = u & 7, b = bkh >> 2, kh = bkh & 3;
    const int h = kh * 4 + ((u >> 3) & 3);
    const int j = u >> 5;
    const int a = sel ? (15 - j) : j;
    const int q0 = a * 128;
    const int nt = 2 * a + 2;

    const float sc = 0.08838834764831845f;
    const float c0 = 0.20762050593045702f;        // log2(10000)/64

    // Q fragments: load raw, apply RoPE in registers (pairs lane-local), pre-scale
    const int qrow = q0 + wave * 16 + l15;
    u16x8 raw[4];
#pragma unroll
    for (int c = 0; c < 4; c++)
        raw[c] = *(const u16x8*)(qkv + (size_t)(b * T_SEQ + qrow) * 3072
                                 + h * 128 + c * 32 + hl * 8);
    const float tpos = (float)(qrow + pos[0]);
    u16x8 qv[4];
#pragma unroll
    for (int c = 0; c < 2; c++)
#pragma unroll
        for (int e = 0; e < 8; e++) {
            int d = c * 32 + hl * 8 + e;          // 0..63
            int i = d >> 1;
            float fA = tpos * exp2f(-(float)i * c0);
            float fB = tpos * exp2f(-(float)(32 + i) * c0);
            float x1 = bf2f(raw[c][e]), x2 = bf2f(raw[c + 2][e]);
            qv[c][e]     = f2bf((x1 * cosf(fA) - x2 * sinf(fA)) * sc);
            qv[c + 2][e] = f2bf((x2 * cosf(fB) + x1 * sinf(fB)) * sc);
        }
    bf16x8 qf[4];
#pragma unroll
    for (int c = 0; c < 4; c++) qf[c] = *(bf16x8*)&qv[c];

    u16x8 onesu;
#pragma unroll
    for (int e = 0; e < 8; e++) onesu[e] = 0x3F80;
    const bf16x8 onesf = *(bf16x8*)&onesu;

    float mrow[4];
    f32x4 o[8];
    f32x4 osum;
    f32x4 z = {0.f, 0.f, 0.f, 0.f};
#pragma unroll
    for (int r = 0; r < 4; r++) mrow[r] = -1e30f;
    osum = z;
#pragma unroll
    for (int n8 = 0; n8 < 8; n8++) o[n8] = z;

    asm volatile("s_waitcnt vmcnt(0)" ::: "memory");

    const u16* kgbase = qkv + (size_t)(b * T_SEQ) * 3072 + 2048 + kh * 128;
    const u16* vgbase = vt + (size_t)(b * 4 + kh) * 128 * 2048;

#pragma unroll
    for (int p = 0; p < 2; p++) {
        int i = p * 512 + t;
        int row = i >> 4, c = i & 15;
        gload_lds16(kgbase + (size_t)row * 3072 + ((c ^ (row & 7)) * 8), (u16*)sK[0] + i * 8);
    }

    int cur = 0;
    for (int it = 0; it < nt; ++it) {
        const int kv0 = it * 64;
        const int kvn = (it + 1 < nt) ? kv0 + 64 : kv0;
#pragma unroll
        for (int p = 0; p < 2; p++) {
            int i = p * 512 + t;
            int row = i >> 3, c = i & 7;
            gload_lds16(vgbase + (size_t)row * 2048 + kv0 + ((c ^ (row & 7)) * 8), sV + i * 8);
        }
#pragma unroll
        for (int p = 0; p < 2; p++) {
            int i = p * 512 + t;
            int row = i >> 4, c = i & 15;
            gload_lds16(kgbase + (size_t)(kvn + row) * 3072 + ((c ^ (row & 7)) * 8),
                        (u16*)sK[cur ^ 1] + i * 8);
        }
        asm volatile("s_waitcnt vmcnt(4)" ::: "memory");   // K(t) landed
        __builtin_amdgcn_s_barrier();

        // S = Q K^T  (16 rows x 64 cols per wave)
        f32x4 sA[4];
#pragma unroll
        for (int n = 0; n < 4; n++) sA[n] = z;
#pragma unroll
        for (int n = 0; n < 4; n++)
#pragma unroll
            for (int c = 0; c < 4; c++) {
                int row = n * 16 + l15;
                bf16x8 kf = *(const bf16x8*)&sK[cur][row * 128 + (((c * 4 + hl) ^ (row & 7)) * 8)];
                sA[n] = __builtin_amdgcn_mfma_f32_16x16x32_bf16(qf[c], kf, sA[n], 0, 0, 0);
            }

        // online softmax: interior tiles skip causal mask entirely (wave-uniform)
        const bool full = (kv0 + 63 <= q0 + wave * 16);
        if (full) {
#pragma unroll
            for (int r = 0; r < 4; r++) {
                float pmax = fmaxf(fmaxf(sA[0][r], sA[1][r]), fmaxf(sA[2][r], sA[3][r]));
                if (__builtin_expect(__any(pmax > mrow[r] + 8.f), 0)) {
                    float mx = pmax;
#pragma unroll
                    for (int off = 1; off < 16; off <<= 1) mx = fmaxf(mx, __shfl_xor(mx, off));
                    float mnew = fmaxf(mrow[r], mx);
                    float alpha = __expf(mrow[r] - mnew);
                    mrow[r] = mnew;
#pragma unroll
                    for (int n8 = 0; n8 < 8; n8++) o[n8][r] *= alpha;
                    osum[r] *= alpha;
                }
#pragma unroll
                for (int n = 0; n < 4; n++)
                    sP[(wave * 16 + hl * 4 + r) * 72 + n * 16 + l15] =
                        (__bf16)__expf(sA[n][r] - mrow[r]);
            }
        } else {
#pragma unroll
            for (int r = 0; r < 4; r++) {
                const int grow = q0 + wave * 16 + hl * 4 + r;
                float mv[4];
#pragma unroll
                for (int n = 0; n < 4; n++)
                    mv[n] = (kv0 + n * 16 + l15 <= grow) ? sA[n][r] : -1e30f;
                float pmax = fmaxf(fmaxf(mv[0], mv[1]), fmaxf(mv[2], mv[3]));
                if (__builtin_expect(__any(pmax > mrow[r] + 8.f), 0)) {
                    float mx = pmax;
#pragma unroll
                    for (int off = 1; off < 16; off <<= 1) mx = fmaxf(mx, __shfl_xor(mx, off));
                    float mnew = fmaxf(mrow[r], mx);
                    float alpha = __expf(mrow[r] - mnew);
                    mrow[r] = mnew;
#pragma unroll
                    for (int n8 = 0; n8 < 8; n8++) o[n8][r] *= alpha;
                    osum[r] *= alpha;
                }
#pragma unroll
                for (int n = 0; n < 4; n++)
                    sP[(wave * 16 + hl * 4 + r) * 72 + n * 16 + l15] =
                        (__bf16)__expf(mv[n] - mrow[r]);
            }
        }

        asm volatile("s_waitcnt vmcnt(2)" ::: "memory");   // V(t) landed
        __builtin_amdgcn_s_barrier();

        bf16x8 pa[2];
#pragma unroll
        for (int k2 = 0; k2 < 2; k2++)
            pa[k2] = *(const bf16x8*)&sP[(wave * 16 + l15) * 72 + k2 * 32 + hl * 8];
#pragma unroll
        for (int k2 = 0; k2 < 2; k2++)
            osum = __builtin_amdgcn_mfma_f32_16x16x32_bf16(pa[k2], onesf, osum, 0, 0, 0);
#pragma unroll
        for (int n8 = 0; n8 < 8; n8++)
#pragma unroll
            for (int k2 = 0; k2 < 2; k2++) {
                int d = n8 * 16 + l15;
                bf16x8 vf = *(const bf16x8*)&sV[d * 64 + (((k2 * 4 + hl) ^ (d & 7)) * 8)];
                o[n8] = __builtin_amdgcn_mfma_f32_16x16x32_bf16(pa[k2], vf, o[n8], 0, 0, 0);
            }
        __builtin_amdgcn_s_barrier();
        cur ^= 1;
    }

#pragma unroll
    for (int r = 0; r < 4; r++) {
        float inv = 1.f / osum[r];
        int orow = b * T_SEQ + q0 + wave * 16 + hl * 4 + r;
#pragma unroll
        for (int n8 = 0; n8 < 8; n8++)
            out[(size_t)orow * 2048 + h * 128 + n8 * 16 + l15] = f2bf(o[n8][r] * inv);
    }
}

extern "C" void kernel_launch(void* const* d_in, const int* in_sizes, int n_in,
                              void* d_out, int out_size, void* d_ws, size_t ws_size,
                              hipStream_t stream) {
    const float* x  = (const float*)d_in[0];
    const float* Wq = (const float*)d_in[1];
    const float* Wk = (const float*)d_in[2];
    const float* Wv = (const float*)d_in[3];
    const float* Wp = (const float*)d_in[4];
    const int*   pos = (const int*)d_in[5];

    char* ws = (char*)d_ws;
    u16* xbf   = (u16*)(ws);                        // 4096*2048 bf16
    u16* WtQKV = (u16*)(ws + 16777216);             // 3072*2048 bf16
    u16* WtP   = (u16*)(ws + 29360128);             // 2048*2048 bf16
    u16* QKV   = (u16*)(ws + 37748736);             // 4096*3072 bf16
    u16* Vt    = (u16*)(ws + 62914560);             // 2*4*128*2048 bf16
    u16* AO    = (u16*)(ws + 67108864);             // 4096*2048 bf16

    prep_all<<<4096 + 2560, 256, 0, stream>>>(x, xbf, Wq, Wk, Wv, Wp, WtQKV, WtP);
    gemm_qkv<<<256, 512, 0, stream>>>(xbf, WtQKV, QKV, 4096, 3072, 2048);
    rope_vtrans<<<512 + 1024, 256, 0, stream>>>(QKV, Vt, pos);
    attn<<<512, 512, 0, stream>>>(QKV, Vt, AO, pos);
    gemm_proj<<<256, 512, 0, stream>>>(AO, WtP, (float*)d_out, 4096, 2048, 2048);
}

// Round 21
// 177.552 us; speedup vs baseline: 1.0889x; 1.0282x over previous
//
#include <hip/hip_runtime.h>
#include <hip/hip_bf16.h>
#include <stdint.h>

typedef unsigned short u16;
typedef float f32x4 __attribute__((ext_vector_type(4)));
typedef __bf16 bf16x8 __attribute__((ext_vector_type(8)));
typedef unsigned short u16x8 __attribute__((ext_vector_type(8)));
typedef unsigned short u16x4 __attribute__((ext_vector_type(4)));
typedef float f32x4v __attribute__((ext_vector_type(4)));

#define T_SEQ 2048

__device__ __forceinline__ u16 f2bf(float f) {
    unsigned int u = __float_as_uint(f);
    unsigned int r = (u + 0x7fffu + ((u >> 16) & 1u)) >> 16;
    return (u16)r;
}
__device__ __forceinline__ float bf2f(u16 b) {
    return __uint_as_float(((unsigned int)b) << 16);
}

__device__ __forceinline__ void gload_lds16(const void* g, void* l) {
    __builtin_amdgcn_global_load_lds(
        (__attribute__((address_space(1))) void*)(g),
        (__attribute__((address_space(3))) void*)(l), 16, 0, 0);
}

// ---------- fused preprocessing: x cast (blocks 0..4095) + W transposes ----------
__global__ void prep_all(const float* __restrict__ x, u16* __restrict__ xbf,
                         const float* __restrict__ Wq, const float* __restrict__ Wk,
                         const float* __restrict__ Wv, const float* __restrict__ Wp,
                         u16* __restrict__ WtQKV, u16* __restrict__ WtP) {
    __shared__ alignas(16) float sW[64 * 68];
    const int t = threadIdx.x;
    const int bid = blockIdx.x;
    if (bid < 4096) {
        int i = bid * 256 + t;
        const f32x4v* p = (const f32x4v*)(x + (size_t)i * 8);
        f32x4v a = p[0], bb = p[1];
        u16x8 v;
        v[0]=f2bf(a.x); v[1]=f2bf(a.y); v[2]=f2bf(a.z); v[3]=f2bf(a.w);
        v[4]=f2bf(bb.x); v[5]=f2bf(bb.y); v[6]=f2bf(bb.z); v[7]=f2bf(bb.w);
        *(u16x8*)(xbf + (size_t)i * 8) = v;
        return;
    }
    const int rem = bid - 4096;
    const int y = rem >> 5;
    const float* W; u16* dst; int N; int n0;
    if (y < 32)      { W = Wq; dst = WtQKV;                       N = 2048; n0 = y * 64; }
    else if (y < 40) { W = Wk; dst = WtQKV + (size_t)2048 * 2048; N = 512;  n0 = (y - 32) * 64; }
    else if (y < 48) { W = Wv; dst = WtQKV + (size_t)2560 * 2048; N = 512;  n0 = (y - 40) * 64; }
    else             { W = Wp; dst = WtP;                         N = 2048; n0 = (y - 48) * 64; }
    const int k0 = (rem & 31) * 64;
#pragma unroll
    for (int i = 0; i < 4; i++) {
        int kr = i * 16 + (t >> 4), nc = (t & 15) * 4;
        *(f32x4v*)&sW[kr * 68 + nc] = *(const f32x4v*)&W[(size_t)(k0 + kr) * N + n0 + nc];
    }
    __syncthreads();
#pragma unroll
    for (int i = 0; i < 2; i++) {
        int nr = i * 32 + (t >> 3), kc = (t & 7) * 8;
        u16x8 v;
#pragma unroll
        for (int j = 0; j < 8; j++) v[j] = f2bf(sW[(kc + j) * 68 + nr]);
        *(u16x8*)&dst[(size_t)(n0 + nr) * 2048 + k0 + kc] = v;
    }
}

// ---------- RoPE trig table: ctab[qrow][i] = (cosA, sinA, cosB, sinB) ----------
// 2048 x 32 float4 = 1 MB, written into the (dead after gemm_qkv) xbf region.
__global__ void rope_tab(f32x4v* __restrict__ ctab, const int* __restrict__ pos) {
    int tid = blockIdx.x * 256 + threadIdx.x;    // 65536 = 2048 x 32
    int qrow = tid >> 5, i = tid & 31;
    float tpos = (float)(qrow + pos[0]);
    const float c0 = 0.20762050593045702f;       // log2(10000)/64
    float fA = tpos * exp2f(-(float)i * c0);
    float fB = tpos * exp2f(-(float)(32 + i) * c0);
    f32x4v w;
    w.x = cosf(fA); w.y = sinf(fA); w.z = cosf(fB); w.w = sinf(fB);
    ctab[tid] = w;
}

// ======== shared staging helpers (XOR-swizzled content, linear LDS) ========
__device__ __forceinline__ void stage_rows(const u16* g, u16* lds, int R, int kcol0, int K, int t) {
    int row = R + (t >> 3);
    int u = t & 7;
    gload_lds16(g + (size_t)row * K + kcol0 + ((u ^ (row & 7)) * 8), lds + row * 64 + u * 8);
}
__device__ __forceinline__ void stage_half256(const u16* g, u16* lds, int half, int j, int kcol0, int K, int t) {
    int idx = j * 512 + t;
    int group = idx >> 8;
    int r32 = (idx >> 3) & 31;
    int row = group * 64 + half * 32 + r32;
    int u = idx & 7;
    gload_lds16(g + (size_t)row * K + kcol0 + ((u ^ (row & 7)) * 8), lds + row * 64 + u * 8);
}
__device__ __forceinline__ bf16x8 lds_ld(const u16* lds, int row, int kc, int hl) {
    return *(const bf16x8*)&lds[row * 64 + (((kc * 4 + hl) ^ (row & 7)) * 8)];
}

// ================= QKV GEMM: 256x192 tiles, 256 blocks (1/CU) =================
__global__ __launch_bounds__(512, 2) void gemm_qkv(const u16* __restrict__ A, const u16* __restrict__ Bt,
                                                   u16* __restrict__ C, int M, int N, int K) {
    __shared__ alignas(16) u16 ldsA[2][256 * 64];
    __shared__ alignas(16) u16 ldsB[2][192 * 64];
    const int t = threadIdx.x, wave = t >> 6, lane = t & 63;
    const int l15 = lane & 15, hl = lane >> 4;
    const int wr = wave >> 2, wc = wave & 3;

    const int f = blockIdx.x;
    const int swz = (f & 7) * 32 + (f >> 3);
    const int bx = swz & 15, by = swz >> 4;
    const int m0 = bx * 256, n0 = by * 192;

    const u16* gA = A + (size_t)m0 * K;
    const u16* gB = Bt + (size_t)n0 * K;

    f32x4 acc[8][3];
    f32x4 z = {0.f, 0.f, 0.f, 0.f};
#pragma unroll
    for (int m = 0; m < 8; m++)
#pragma unroll
        for (int n = 0; n < 3; n++) acc[m][n] = z;

    stage_rows(gA, ldsA[0], 0, 0, K, t);
    stage_rows(gA, ldsA[0], 128, 0, K, t);
    stage_rows(gB, ldsB[0], 0, 0, K, t);
    stage_rows(gB, ldsB[0], 64, 0, K, t);
    stage_rows(gB, ldsB[0], 128, 0, K, t);
    stage_rows(gA, ldsA[0], 64, 0, K, t);
    stage_rows(gA, ldsA[0], 192, 0, K, t);

    const int KT = K >> 6;
    for (int kt = 0; kt < KT; ++kt) {
        const int c = kt & 1;
        const int kn = (kt + 1 < KT) ? (kt + 1) * 64 : kt * 64;
        const u16* lAc = ldsA[c];
        const u16* lBc = ldsB[c];
        u16* lAn = ldsA[c ^ 1];
        u16* lBn = ldsB[c ^ 1];

        bf16x8 aF[4][2], bF[3][2];

        asm volatile("s_waitcnt vmcnt(2)" ::: "memory");
        __builtin_amdgcn_s_barrier();
#pragma unroll
        for (int mi = 0; mi < 4; mi++)
#pragma unroll
            for (int kc = 0; kc < 2; kc++)
                aF[mi][kc] = lds_ld(lAc, wr * 128 + mi * 16 + l15, kc, hl);
#pragma unroll
        for (int n = 0; n < 3; n++)
#pragma unroll
            for (int kc = 0; kc < 2; kc++)
                bF[n][kc] = lds_ld(lBc, wc * 48 + n * 16 + l15, kc, hl);
        stage_rows(gA, lAn, 0, kn, K, t);
        stage_rows(gA, lAn, 128, kn, K, t);
        stage_rows(gB, lBn, 0, kn, K, t);
        __builtin_amdgcn_s_setprio(1);
#pragma unroll
        for (int mi = 0; mi < 4; mi++)
#pragma unroll
            for (int n = 0; n < 3; n++)
#pragma unroll
                for (int kc = 0; kc < 2; kc++)
                    acc[mi][n] = __builtin_amdgcn_mfma_f32_16x16x32_bf16(aF[mi][kc], bF[n][kc], acc[mi][n], 0, 0, 0);
        __builtin_amdgcn_s_setprio(0);

        asm volatile("s_waitcnt vmcnt(3)" ::: "memory");
        __builtin_amdgcn_s_barrier();
#pragma unroll
        for (int mi = 0; mi < 4; mi++)
#pragma unroll
            for (int kc = 0; kc < 2; kc++)
                aF[mi][kc] = lds_ld(lAc, wr * 128 + 64 + mi * 16 + l15, kc, hl);
        stage_rows(gB, lBn, 64, kn, K, t);
        stage_rows(gB, lBn, 128, kn, K, t);
        stage_rows(gA, lAn, 64, kn, K, t);
        stage_rows(gA, lAn, 192, kn, K, t);
        __builtin_amdgcn_s_setprio(1);
#pragma unroll
        for (int mi = 0; mi < 4; mi++)
#pragma unroll
            for (int n = 0; n < 3; n++)
#pragma unroll
                for (int kc = 0; kc < 2; kc++)
                    acc[4 + mi][n] = __builtin_amdgcn_mfma_f32_16x16x32_bf16(aF[mi][kc], bF[n][kc], acc[4 + mi][n], 0, 0, 0);
        __builtin_amdgcn_s_setprio(0);
    }

#pragma unroll
    for (int m = 0; m < 8; m++)
#pragma unroll
        for (int n = 0; n < 3; n++)
#pragma unroll
            for (int r = 0; r < 4; r++) {
                int row = m0 + wr * 128 + m * 16 + hl * 4 + r;
                int col = n0 + wc * 48 + n * 16 + l15;
                C[(size_t)row * N + col] = f2bf(acc[m][n][r]);
            }
}

// ================= proj GEMM: 128x256 tiles, 256 blocks (1/CU), f32 out =================
__global__ __launch_bounds__(512, 2) void gemm_proj(const u16* __restrict__ A, const u16* __restrict__ Bt,
                                                    float* __restrict__ C, int M, int N, int K) {
    __shared__ alignas(16) u16 ldsA[2][128 * 64];
    __shared__ alignas(16) u16 ldsB[2][256 * 64];
    const int t = threadIdx.x, wave = t >> 6, lane = t & 63;
    const int l15 = lane & 15, hl = lane >> 4;
    const int wr = wave >> 2, wc = wave & 3;

    const int f = blockIdx.x;
    const int swz = (f & 7) * 32 + (f >> 3);
    const int bx = swz & 31, by = swz >> 5;
    const int m0 = bx * 128, n0 = by * 256;

    const u16* gA = A + (size_t)m0 * K;
    const u16* gB = Bt + (size_t)n0 * K;

    f32x4 acc[4][4];
    f32x4 z = {0.f, 0.f, 0.f, 0.f};
#pragma unroll
    for (int m = 0; m < 4; m++)
#pragma unroll
        for (int n = 0; n < 4; n++) acc[m][n] = z;

    stage_rows(gA, ldsA[0], 0, 0, K, t);
    stage_rows(gA, ldsA[0], 64, 0, K, t);
    stage_half256(gB, ldsB[0], 0, 0, 0, K, t);
    stage_half256(gB, ldsB[0], 0, 1, 0, K, t);
    stage_half256(gB, ldsB[0], 1, 0, 0, K, t);
    stage_half256(gB, ldsB[0], 1, 1, 0, K, t);

    const int KT = K >> 6;
    for (int kt = 0; kt < KT; ++kt) {
        const int c = kt & 1;
        const int kn = (kt + 1 < KT) ? (kt + 1) * 64 : kt * 64;
        const u16* lAc = ldsA[c];
        const u16* lBc = ldsB[c];
        u16* lAn = ldsA[c ^ 1];
        u16* lBn = ldsB[c ^ 1];

        bf16x8 aF[4][2], bF[2][2];

        asm volatile("s_waitcnt vmcnt(2)" ::: "memory");
        __builtin_amdgcn_s_barrier();
#pragma unroll
        for (int mi = 0; mi < 4; mi++)
#pragma unroll
            for (int kc = 0; kc < 2; kc++)
                aF[mi][kc] = lds_ld(lAc, wr * 64 + mi * 16 + l15, kc, hl);
#pragma unroll
        for (int n = 0; n < 2; n++)
#pragma unroll
            for (int kc = 0; kc < 2; kc++)
                bF[n][kc] = lds_ld(lBc, wc * 64 + n * 16 + l15, kc, hl);
        stage_rows(gA, lAn, 0, kn, K, t);
        stage_rows(gA, lAn, 64, kn, K, t);
        stage_half256(gB, lBn, 0, 0, kn, K, t);
        stage_half256(gB, lBn, 0, 1, kn, K, t);
        __builtin_amdgcn_s_setprio(1);
#pragma unroll
        for (int mi = 0; mi < 4; mi++)
#pragma unroll
            for (int n = 0; n < 2; n++)
#pragma unroll
                for (int kc = 0; kc < 2; kc++)
                    acc[mi][n] = __builtin_amdgcn_mfma_f32_16x16x32_bf16(aF[mi][kc], bF[n][kc], acc[mi][n], 0, 0, 0);
        __builtin_amdgcn_s_setprio(0);

        asm volatile("s_waitcnt vmcnt(4)" ::: "memory");
        __builtin_amdgcn_s_barrier();
#pragma unroll
        for (int n = 0; n < 2; n++)
#pragma unroll
            for (int kc = 0; kc < 2; kc++)
                bF[n][kc] = lds_ld(lBc, wc * 64 + 32 + n * 16 + l15, kc, hl);
        stage_half256(gB, lBn, 1, 0, kn, K, t);
        stage_half256(gB, lBn, 1, 1, kn, K, t);
        __builtin_amdgcn_s_setprio(1);
#pragma unroll
        for (int mi = 0; mi < 4; mi++)
#pragma unroll
            for (int n = 0; n < 2; n++)
#pragma unroll
                for (int kc = 0; kc < 2; kc++)
                    acc[mi][2 + n] = __builtin_amdgcn_mfma_f32_16x16x32_bf16(aF[mi][kc], bF[n][kc], acc[mi][2 + n], 0, 0, 0);
        __builtin_amdgcn_s_setprio(0);
    }

#pragma unroll
    for (int m = 0; m < 4; m++)
#pragma unroll
        for (int n = 0; n < 4; n++)
#pragma unroll
            for (int r = 0; r < 4; r++) {
                int row = m0 + wr * 64 + m * 16 + hl * 4 + r;
                int col = n0 + wc * 64 + n * 16 + l15;
                C[(size_t)row * N + col] = acc[m][n][r];
            }
}

// ---------------- fused RoPE (K heads only; Q roped in attn) + V transpose ----------------
__global__ void rope_vtrans(u16* __restrict__ qkv, u16* __restrict__ vt,
                            const int* __restrict__ pos) {
    __shared__ alignas(16) u16 sT[64 * 72];
    const int t = threadIdx.x;
    if (blockIdx.x < 512) {
        const int f = blockIdx.x;
        const int t0 = (f & 31) * 64;
        const int d0 = ((f >> 5) & 1) * 64;
        const int kh = (f >> 6) & 3, b = f >> 8;
#pragma unroll
        for (int i = 0; i < 2; i++) {
            int tr = i * 32 + (t >> 3), dc = (t & 7) * 8;
            *(u16x8*)&sT[tr * 72 + dc] =
                *(const u16x8*)&qkv[(size_t)(b * T_SEQ + t0 + tr) * 3072 + 2560 + kh * 128 + d0 + dc];
        }
        __syncthreads();
#pragma unroll
        for (int i = 0; i < 2; i++) {
            int dr = i * 32 + (t >> 3), tc = (t & 7) * 8;
            u16x8 v;
#pragma unroll
            for (int j = 0; j < 8; j++) v[j] = sT[(tc + j) * 72 + dr];
            *(u16x8*)&vt[((size_t)(b * 4 + kh) * 128 + d0 + dr) * 2048 + t0 + tc] = v;
        }
    } else {
        // rope on K heads only: 4 slices (cols 2048..2560), 16 threads per (row, slice)
        int tid = (blockIdx.x - 512) * 256 + t;
        int j4 = tid & 15;
        int rest = tid >> 4;
        int slice = rest & 3;
        int row = rest >> 2;
        if (row >= 2 * T_SEQ) return;
        float tpos = (float)((row % T_SEQ) + pos[0]);
        int base = 2048 + slice * 128;
        u16* p = qkv + (size_t)row * 3072 + base + j4 * 4;
        u16x4 lo = *(const u16x4*)p;
        u16x4 hi = *(const u16x4*)(p + 64);
        const float c0 = 0.20762050593045702f;   // log2(10000)/64
        u16x4 olo, ohi;
#pragma unroll
        for (int e = 0; e < 4; e++) {
            int i = (j4 * 4 + e) >> 1;
            float fA = tpos * exp2f(-(float)i * c0);
            float fB = tpos * exp2f(-(float)(32 + i) * c0);
            float x1 = bf2f(lo[e]), x2 = bf2f(hi[e]);
            olo[e] = f2bf(x1 * cosf(fA) - x2 * sinf(fA));
            ohi[e] = f2bf(x2 * cosf(fB) + x1 * sinf(fB));
        }
        *(u16x4*)p = olo;
        *(u16x4*)(p + 64) = ohi;
    }
}

// ---------------- causal GQA flash attention: 8 waves x 16 q-rows ----------------
// R16-proven structure; Q-RoPE applied in registers via precomputed trig table
// (pairs lane-local: d = c*32+hl*8+e pairs with d+64 at c+2; i = c*16+hl*4+(e>>1)).
__global__ __launch_bounds__(512, 4) void attn(const u16* __restrict__ qkv,
                                               const u16* __restrict__ vt,
                                               u16* __restrict__ out,
                                               const f32x4v* __restrict__ ctab) {
    __shared__ alignas(16) u16 sK[2][8192];       // [64][128] XOR-swizzled content
    __shared__ alignas(16) u16 sV[8192];          // [128][64] XOR-swizzled content
    __shared__ alignas(16) __bf16 sP[128 * 72];
    const int t = threadIdx.x, wave = t >> 6, lane = t & 63;
    const int l15 = lane & 15, hl = lane >> 4;

    const int f = blockIdx.x;
    const int sel = f >> 8, u = f & 255;
    const int bkh = u & 7, b = bkh >> 2, kh = bkh & 3;
    const int h = kh * 4 + ((u >> 3) & 3);
    const int j = u >> 5;
    const int a = sel ? (15 - j) : j;
    const int q0 = a * 128;
    const int nt = 2 * a + 2;

    const float sc = 0.08838834764831845f;

    // Q fragments: load raw, RoPE via table, pre-scale
    const int qrow = q0 + wave * 16 + l15;
    u16x8 raw[4];
#pragma unroll
    for (int c = 0; c < 4; c++)
        raw[c] = *(const u16x8*)(qkv + (size_t)(b * T_SEQ + qrow) * 3072
                                 + h * 128 + c * 32 + hl * 8);
    const f32x4v* ct = ctab + (size_t)qrow * 32;
    u16x8 qv[4];
#pragma unroll
    for (int c = 0; c < 2; c++)
#pragma unroll
        for (int k = 0; k < 4; k++) {
            f32x4v w = ct[c * 16 + hl * 4 + k];   // cosA, sinA, cosB, sinB
#pragma unroll
            for (int par = 0; par < 2; par++) {
                int e = k * 2 + par;
                float x1 = bf2f(raw[c][e]), x2 = bf2f(raw[c + 2][e]);
                qv[c][e]     = f2bf((x1 * w.x - x2 * w.y) * sc);
                qv[c + 2][e] = f2bf((x2 * w.z + x1 * w.w) * sc);
            }
        }
    bf16x8 qf[4];
#pragma unroll
    for (int c = 0; c < 4; c++) qf[c] = *(bf16x8*)&qv[c];

    u16x8 onesu;
#pragma unroll
    for (int e = 0; e < 8; e++) onesu[e] = 0x3F80;
    const bf16x8 onesf = *(bf16x8*)&onesu;

    float mrow[4];
    f32x4 o[8];
    f32x4 osum;
    f32x4 z = {0.f, 0.f, 0.f, 0.f};
#pragma unroll
    for (int r = 0; r < 4; r++) mrow[r] = -1e30f;
    osum = z;
#pragma unroll
    for (int n8 = 0; n8 < 8; n8++) o[n8] = z;

    asm volatile("s_waitcnt vmcnt(0)" ::: "memory");

    const u16* kgbase = qkv + (size_t)(b * T_SEQ) * 3072 + 2048 + kh * 128;
    const u16* vgbase = vt + (size_t)(b * 4 + kh) * 128 * 2048;

#pragma unroll
    for (int p = 0; p < 2; p++) {
        int i = p * 512 + t;
        int row = i >> 4, c = i & 15;
        gload_lds16(kgbase + (size_t)row * 3072 + ((c ^ (row & 7)) * 8), (u16*)sK[0] + i * 8);
    }

    int cur = 0;
    for (int it = 0; it < nt; ++it) {
        const int kv0 = it * 64;
        const int kvn = (it + 1 < nt) ? kv0 + 64 : kv0;
#pragma unroll
        for (int p = 0; p < 2; p++) {
            int i = p * 512 + t;
            int row = i >> 3, c = i & 7;
            gload_lds16(vgbase + (size_t)row * 2048 + kv0 + ((c ^ (row & 7)) * 8), sV + i * 8);
        }
#pragma unroll
        for (int p = 0; p < 2; p++) {
            int i = p * 512 + t;
            int row = i >> 4, c = i & 15;
            gload_lds16(kgbase + (size_t)(kvn + row) * 3072 + ((c ^ (row & 7)) * 8),
                        (u16*)sK[cur ^ 1] + i * 8);
        }
        asm volatile("s_waitcnt vmcnt(4)" ::: "memory");   // K(t) landed
        __builtin_amdgcn_s_barrier();

        // S = Q K^T  (16 rows x 64 cols per wave)
        f32x4 sA[4];
#pragma unroll
        for (int n = 0; n < 4; n++) sA[n] = z;
#pragma unroll
        for (int n = 0; n < 4; n++)
#pragma unroll
            for (int c = 0; c < 4; c++) {
                int row = n * 16 + l15;
                bf16x8 kf = *(const bf16x8*)&sK[cur][row * 128 + (((c * 4 + hl) ^ (row & 7)) * 8)];
                sA[n] = __builtin_amdgcn_mfma_f32_16x16x32_bf16(qf[c], kf, sA[n], 0, 0, 0);
            }

        // online softmax: interior tiles skip causal mask entirely (wave-uniform)
        const bool full = (kv0 + 63 <= q0 + wave * 16);
        if (full) {
#pragma unroll
            for (int r = 0; r < 4; r++) {
                float pmax = fmaxf(fmaxf(sA[0][r], sA[1][r]), fmaxf(sA[2][r], sA[3][r]));
                if (__builtin_expect(__any(pmax > mrow[r] + 8.f), 0)) {
                    float mx = pmax;
#pragma unroll
                    for (int off = 1; off < 16; off <<= 1) mx = fmaxf(mx, __shfl_xor(mx, off));
                    float mnew = fmaxf(mrow[r], mx);
                    float alpha = __expf(mrow[r] - mnew);
                    mrow[r] = mnew;
#pragma unroll
                    for (int n8 = 0; n8 < 8; n8++) o[n8][r] *= alpha;
                    osum[r] *= alpha;
                }
#pragma unroll
                for (int n = 0; n < 4; n++)
                    sP[(wave * 16 + hl * 4 + r) * 72 + n * 16 + l15] =
                        (__bf16)__expf(sA[n][r] - mrow[r]);
            }
        } else {
#pragma unroll
            for (int r = 0; r < 4; r++) {
                const int grow = q0 + wave * 16 + hl * 4 + r;
                float mv[4];
#pragma unroll
                for (int n = 0; n < 4; n++)
                    mv[n] = (kv0 + n * 16 + l15 <= grow) ? sA[n][r] : -1e30f;
                float pmax = fmaxf(fmaxf(mv[0], mv[1]), fmaxf(mv[2], mv[3]));
                if (__builtin_expect(__any(pmax > mrow[r] + 8.f), 0)) {
                    float mx = pmax;
#pragma unroll
                    for (int off = 1; off < 16; off <<= 1) mx = fmaxf(mx, __shfl_xor(mx, off));
                    float mnew = fmaxf(mrow[r], mx);
                    float alpha = __expf(mrow[r] - mnew);
                    mrow[r] = mnew;
#pragma unroll
                    for (int n8 = 0; n8 < 8; n8++) o[n8][r] *= alpha;
                    osum[r] *= alpha;
                }
#pragma unroll
                for (int n = 0; n < 4; n++)
                    sP[(wave * 16 + hl * 4 + r) * 72 + n * 16 + l15] =
                        (__bf16)__expf(mv[n] - mrow[r]);
            }
        }

        asm volatile("s_waitcnt vmcnt(2)" ::: "memory");   // V(t) landed
        __builtin_amdgcn_s_barrier();

        bf16x8 pa[2];
#pragma unroll
        for (int k2 = 0; k2 < 2; k2++)
            pa[k2] = *(const bf16x8*)&sP[(wave * 16 + l15) * 72 + k2 * 32 + hl * 8];
#pragma unroll
        for (int k2 = 0; k2 < 2; k2++)
            osum = __builtin_amdgcn_mfma_f32_16x16x32_bf16(pa[k2], onesf, osum, 0, 0, 0);
#pragma unroll
        for (int n8 = 0; n8 < 8; n8++)
#pragma unroll
            for (int k2 = 0; k2 < 2; k2++) {
                int d = n8 * 16 + l15;
                bf16x8 vf = *(const bf16x8*)&sV[d * 64 + (((k2 * 4 + hl) ^ (d & 7)) * 8)];
                o[n8] = __builtin_amdgcn_mfma_f32_16x16x32_bf16(pa[k2], vf, o[n8], 0, 0, 0);
            }
        __builtin_amdgcn_s_barrier();
        cur ^= 1;
    }

#pragma unroll
    for (int r = 0; r < 4; r++) {
        float inv = 1.f / osum[r];
        int orow = b * T_SEQ + q0 + wave * 16 + hl * 4 + r;
#pragma unroll
        for (int n8 = 0; n8 < 8; n8++)
            out[(size_t)orow * 2048 + h * 128 + n8 * 16 + l15] = f2bf(o[n8][r] * inv);
    }
}

extern "C" void kernel_launch(void* const* d_in, const int* in_sizes, int n_in,
                              void* d_out, int out_size, void* d_ws, size_t ws_size,
                              hipStream_t stream) {
    const float* x  = (const float*)d_in[0];
    const float* Wq = (const float*)d_in[1];
    const float* Wk = (const float*)d_in[2];
    const float* Wv = (const float*)d_in[3];
    const float* Wp = (const float*)d_in[4];
    const int*   pos = (const int*)d_in[5];

    char* ws = (char*)d_ws;
    u16* xbf   = (u16*)(ws);                        // 4096*2048 bf16 (dead after gemm_qkv; reused for ctab)
    u16* WtQKV = (u16*)(ws + 16777216);             // 3072*2048 bf16
    u16* WtP   = (u16*)(ws + 29360128);             // 2048*2048 bf16
    u16* QKV   = (u16*)(ws + 37748736);             // 4096*3072 bf16
    u16* Vt    = (u16*)(ws + 62914560);             // 2*4*128*2048 bf16
    u16* AO    = (u16*)(ws + 67108864);             // 4096*2048 bf16
    f32x4v* ctab = (f32x4v*)(ws);                   // 2048*32 float4 = 1 MB (in dead xbf region)

    prep_all<<<4096 + 2560, 256, 0, stream>>>(x, xbf, Wq, Wk, Wv, Wp, WtQKV, WtP);
    gemm_qkv<<<256, 512, 0, stream>>>(xbf, WtQKV, QKV, 4096, 3072, 2048);
    rope_tab<<<256, 256, 0, stream>>>(ctab, pos);
    rope_vtrans<<<512 + 1024, 256, 0, stream>>>(QKV, Vt, pos);
    attn<<<512, 512, 0, stream>>>(QKV, Vt, AO, ctab);
    gemm_proj<<<256, 512, 0, stream>>>(AO, WtP, (float*)d_out, 4096, 2048, 2048);
}

// Round 22
// 175.486 us; speedup vs baseline: 1.1017x; 1.0118x over previous
//
#include <hip/hip_runtime.h>
#include <hip/hip_bf16.h>
#include <stdint.h>

typedef unsigned short u16;
typedef float f32x4 __attribute__((ext_vector_type(4)));
typedef __bf16 bf16x8 __attribute__((ext_vector_type(8)));
typedef unsigned short u16x8 __attribute__((ext_vector_type(8)));
typedef unsigned short u16x4 __attribute__((ext_vector_type(4)));
typedef float f32x4v __attribute__((ext_vector_type(4)));

#define T_SEQ 2048

__device__ __forceinline__ u16 f2bf(float f) {
    unsigned int u = __float_as_uint(f);
    unsigned int r = (u + 0x7fffu + ((u >> 16) & 1u)) >> 16;
    return (u16)r;
}
__device__ __forceinline__ float bf2f(u16 b) {
    return __uint_as_float(((unsigned int)b) << 16);
}

__device__ __forceinline__ void gload_lds16(const void* g, void* l) {
    __builtin_amdgcn_global_load_lds(
        (__attribute__((address_space(1))) void*)(g),
        (__attribute__((address_space(3))) void*)(l), 16, 0, 0);
}

// ---------- fused preprocessing: x cast (blocks 0..4095) + W transposes ----------
__global__ void prep_all(const float* __restrict__ x, u16* __restrict__ xbf,
                         const float* __restrict__ Wq, const float* __restrict__ Wk,
                         const float* __restrict__ Wv, const float* __restrict__ Wp,
                         u16* __restrict__ WtQKV, u16* __restrict__ WtP) {
    __shared__ alignas(16) float sW[64 * 68];
    const int t = threadIdx.x;
    const int bid = blockIdx.x;
    if (bid < 4096) {
        int i = bid * 256 + t;
        const f32x4v* p = (const f32x4v*)(x + (size_t)i * 8);
        f32x4v a = p[0], bb = p[1];
        u16x8 v;
        v[0]=f2bf(a.x); v[1]=f2bf(a.y); v[2]=f2bf(a.z); v[3]=f2bf(a.w);
        v[4]=f2bf(bb.x); v[5]=f2bf(bb.y); v[6]=f2bf(bb.z); v[7]=f2bf(bb.w);
        *(u16x8*)(xbf + (size_t)i * 8) = v;
        return;
    }
    const int rem = bid - 4096;
    const int y = rem >> 5;
    const float* W; u16* dst; int N; int n0;
    if (y < 32)      { W = Wq; dst = WtQKV;                       N = 2048; n0 = y * 64; }
    else if (y < 40) { W = Wk; dst = WtQKV + (size_t)2048 * 2048; N = 512;  n0 = (y - 32) * 64; }
    else if (y < 48) { W = Wv; dst = WtQKV + (size_t)2560 * 2048; N = 512;  n0 = (y - 40) * 64; }
    else             { W = Wp; dst = WtP;                         N = 2048; n0 = (y - 48) * 64; }
    const int k0 = (rem & 31) * 64;
#pragma unroll
    for (int i = 0; i < 4; i++) {
        int kr = i * 16 + (t >> 4), nc = (t & 15) * 4;
        *(f32x4v*)&sW[kr * 68 + nc] = *(const f32x4v*)&W[(size_t)(k0 + kr) * N + n0 + nc];
    }
    __syncthreads();
#pragma unroll
    for (int i = 0; i < 2; i++) {
        int nr = i * 32 + (t >> 3), kc = (t & 7) * 8;
        u16x8 v;
#pragma unroll
        for (int j = 0; j < 8; j++) v[j] = f2bf(sW[(kc + j) * 68 + nr]);
        *(u16x8*)&dst[(size_t)(n0 + nr) * 2048 + k0 + kc] = v;
    }
}

// ======== shared staging helpers (XOR-swizzled content, linear LDS) ========
__device__ __forceinline__ void stage_rows(const u16* g, u16* lds, int R, int kcol0, int K, int t) {
    int row = R + (t >> 3);
    int u = t & 7;
    gload_lds16(g + (size_t)row * K + kcol0 + ((u ^ (row & 7)) * 8), lds + row * 64 + u * 8);
}
__device__ __forceinline__ void stage_half256(const u16* g, u16* lds, int half, int j, int kcol0, int K, int t) {
    int idx = j * 512 + t;
    int group = idx >> 8;
    int r32 = (idx >> 3) & 31;
    int row = group * 64 + half * 32 + r32;
    int u = idx & 7;
    gload_lds16(g + (size_t)row * K + kcol0 + ((u ^ (row & 7)) * 8), lds + row * 64 + u * 8);
}
__device__ __forceinline__ bf16x8 lds_ld(const u16* lds, int row, int kc, int hl) {
    return *(const bf16x8*)&lds[row * 64 + (((kc * 4 + hl) ^ (row & 7)) * 8)];
}

// ================= QKV GEMM: 256x192 tiles, 256 blocks (1/CU) =================
__global__ __launch_bounds__(512, 2) void gemm_qkv(const u16* __restrict__ A, const u16* __restrict__ Bt,
                                                   u16* __restrict__ C, int M, int N, int K) {
    __shared__ alignas(16) u16 ldsA[2][256 * 64];
    __shared__ alignas(16) u16 ldsB[2][192 * 64];
    const int t = threadIdx.x, wave = t >> 6, lane = t & 63;
    const int l15 = lane & 15, hl = lane >> 4;
    const int wr = wave >> 2, wc = wave & 3;

    const int f = blockIdx.x;
    const int swz = (f & 7) * 32 + (f >> 3);
    const int bx = swz & 15, by = swz >> 4;
    const int m0 = bx * 256, n0 = by * 192;

    const u16* gA = A + (size_t)m0 * K;
    const u16* gB = Bt + (size_t)n0 * K;

    f32x4 acc[8][3];
    f32x4 z = {0.f, 0.f, 0.f, 0.f};
#pragma unroll
    for (int m = 0; m < 8; m++)
#pragma unroll
        for (int n = 0; n < 3; n++) acc[m][n] = z;

    stage_rows(gA, ldsA[0], 0, 0, K, t);
    stage_rows(gA, ldsA[0], 128, 0, K, t);
    stage_rows(gB, ldsB[0], 0, 0, K, t);
    stage_rows(gB, ldsB[0], 64, 0, K, t);
    stage_rows(gB, ldsB[0], 128, 0, K, t);
    stage_rows(gA, ldsA[0], 64, 0, K, t);
    stage_rows(gA, ldsA[0], 192, 0, K, t);

    const int KT = K >> 6;
    for (int kt = 0; kt < KT; ++kt) {
        const int c = kt & 1;
        const int kn = (kt + 1 < KT) ? (kt + 1) * 64 : kt * 64;
        const u16* lAc = ldsA[c];
        const u16* lBc = ldsB[c];
        u16* lAn = ldsA[c ^ 1];
        u16* lBn = ldsB[c ^ 1];

        bf16x8 aF[4][2], bF[3][2];

        asm volatile("s_waitcnt vmcnt(2)" ::: "memory");
        __builtin_amdgcn_s_barrier();
#pragma unroll
        for (int mi = 0; mi < 4; mi++)
#pragma unroll
            for (int kc = 0; kc < 2; kc++)
                aF[mi][kc] = lds_ld(lAc, wr * 128 + mi * 16 + l15, kc, hl);
#pragma unroll
        for (int n = 0; n < 3; n++)
#pragma unroll
            for (int kc = 0; kc < 2; kc++)
                bF[n][kc] = lds_ld(lBc, wc * 48 + n * 16 + l15, kc, hl);
        stage_rows(gA, lAn, 0, kn, K, t);
        stage_rows(gA, lAn, 128, kn, K, t);
        stage_rows(gB, lBn, 0, kn, K, t);
        __builtin_amdgcn_s_setprio(1);
#pragma unroll
        for (int mi = 0; mi < 4; mi++)
#pragma unroll
            for (int n = 0; n < 3; n++)
#pragma unroll
                for (int kc = 0; kc < 2; kc++)
                    acc[mi][n] = __builtin_amdgcn_mfma_f32_16x16x32_bf16(aF[mi][kc], bF[n][kc], acc[mi][n], 0, 0, 0);
        __builtin_amdgcn_s_setprio(0);

        asm volatile("s_waitcnt vmcnt(3)" ::: "memory");
        __builtin_amdgcn_s_barrier();
#pragma unroll
        for (int mi = 0; mi < 4; mi++)
#pragma unroll
            for (int kc = 0; kc < 2; kc++)
                aF[mi][kc] = lds_ld(lAc, wr * 128 + 64 + mi * 16 + l15, kc, hl);
        stage_rows(gB, lBn, 64, kn, K, t);
        stage_rows(gB, lBn, 128, kn, K, t);
        stage_rows(gA, lAn, 64, kn, K, t);
        stage_rows(gA, lAn, 192, kn, K, t);
        __builtin_amdgcn_s_setprio(1);
#pragma unroll
        for (int mi = 0; mi < 4; mi++)
#pragma unroll
            for (int n = 0; n < 3; n++)
#pragma unroll
                for (int kc = 0; kc < 2; kc++)
                    acc[4 + mi][n] = __builtin_amdgcn_mfma_f32_16x16x32_bf16(aF[mi][kc], bF[n][kc], acc[4 + mi][n], 0, 0, 0);
        __builtin_amdgcn_s_setprio(0);
    }

#pragma unroll
    for (int m = 0; m < 8; m++)
#pragma unroll
        for (int n = 0; n < 3; n++)
#pragma unroll
            for (int r = 0; r < 4; r++) {
                int row = m0 + wr * 128 + m * 16 + hl * 4 + r;
                int col = n0 + wc * 48 + n * 16 + l15;
                C[(size_t)row * N + col] = f2bf(acc[m][n][r]);
            }
}

// ================= proj GEMM: 128x256 tiles, 256 blocks (1/CU), f32 out =================
__global__ __launch_bounds__(512, 2) void gemm_proj(const u16* __restrict__ A, const u16* __restrict__ Bt,
                                                    float* __restrict__ C, int M, int N, int K) {
    __shared__ alignas(16) u16 ldsA[2][128 * 64];
    __shared__ alignas(16) u16 ldsB[2][256 * 64];
    const int t = threadIdx.x, wave = t >> 6, lane = t & 63;
    const int l15 = lane & 15, hl = lane >> 4;
    const int wr = wave >> 2, wc = wave & 3;

    const int f = blockIdx.x;
    const int swz = (f & 7) * 32 + (f >> 3);
    const int bx = swz & 31, by = swz >> 5;
    const int m0 = bx * 128, n0 = by * 256;

    const u16* gA = A + (size_t)m0 * K;
    const u16* gB = Bt + (size_t)n0 * K;

    f32x4 acc[4][4];
    f32x4 z = {0.f, 0.f, 0.f, 0.f};
#pragma unroll
    for (int m = 0; m < 4; m++)
#pragma unroll
        for (int n = 0; n < 4; n++) acc[m][n] = z;

    stage_rows(gA, ldsA[0], 0, 0, K, t);
    stage_rows(gA, ldsA[0], 64, 0, K, t);
    stage_half256(gB, ldsB[0], 0, 0, 0, K, t);
    stage_half256(gB, ldsB[0], 0, 1, 0, K, t);
    stage_half256(gB, ldsB[0], 1, 0, 0, K, t);
    stage_half256(gB, ldsB[0], 1, 1, 0, K, t);

    const int KT = K >> 6;
    for (int kt = 0; kt < KT; ++kt) {
        const int c = kt & 1;
        const int kn = (kt + 1 < KT) ? (kt + 1) * 64 : kt * 64;
        const u16* lAc = ldsA[c];
        const u16* lBc = ldsB[c];
        u16* lAn = ldsA[c ^ 1];
        u16* lBn = ldsB[c ^ 1];

        bf16x8 aF[4][2], bF[2][2];

        asm volatile("s_waitcnt vmcnt(2)" ::: "memory");
        __builtin_amdgcn_s_barrier();
#pragma unroll
        for (int mi = 0; mi < 4; mi++)
#pragma unroll
            for (int kc = 0; kc < 2; kc++)
                aF[mi][kc] = lds_ld(lAc, wr * 64 + mi * 16 + l15, kc, hl);
#pragma unroll
        for (int n = 0; n < 2; n++)
#pragma unroll
            for (int kc = 0; kc < 2; kc++)
                bF[n][kc] = lds_ld(lBc, wc * 64 + n * 16 + l15, kc, hl);
        stage_rows(gA, lAn, 0, kn, K, t);
        stage_rows(gA, lAn, 64, kn, K, t);
        stage_half256(gB, lBn, 0, 0, kn, K, t);
        stage_half256(gB, lBn, 0, 1, kn, K, t);
        __builtin_amdgcn_s_setprio(1);
#pragma unroll
        for (int mi = 0; mi < 4; mi++)
#pragma unroll
            for (int n = 0; n < 2; n++)
#pragma unroll
                for (int kc = 0; kc < 2; kc++)
                    acc[mi][n] = __builtin_amdgcn_mfma_f32_16x16x32_bf16(aF[mi][kc], bF[n][kc], acc[mi][n], 0, 0, 0);
        __builtin_amdgcn_s_setprio(0);

        asm volatile("s_waitcnt vmcnt(4)" ::: "memory");
        __builtin_amdgcn_s_barrier();
#pragma unroll
        for (int n = 0; n < 2; n++)
#pragma unroll
            for (int kc = 0; kc < 2; kc++)
                bF[n][kc] = lds_ld(lBc, wc * 64 + 32 + n * 16 + l15, kc, hl);
        stage_half256(gB, lBn, 1, 0, kn, K, t);
        stage_half256(gB, lBn, 1, 1, kn, K, t);
        __builtin_amdgcn_s_setprio(1);
#pragma unroll
        for (int mi = 0; mi < 4; mi++)
#pragma unroll
            for (int n = 0; n < 2; n++)
#pragma unroll
                for (int kc = 0; kc < 2; kc++)
                    acc[mi][2 + n] = __builtin_amdgcn_mfma_f32_16x16x32_bf16(aF[mi][kc], bF[n][kc], acc[mi][2 + n], 0, 0, 0);
        __builtin_amdgcn_s_setprio(0);
    }

#pragma unroll
    for (int m = 0; m < 4; m++)
#pragma unroll
        for (int n = 0; n < 4; n++)
#pragma unroll
            for (int r = 0; r < 4; r++) {
                int row = m0 + wr * 64 + m * 16 + hl * 4 + r;
                int col = n0 + wc * 64 + n * 16 + l15;
                C[(size_t)row * N + col] = acc[m][n][r];
            }
}

// ---- fused: V transpose (blocks<512) + K RoPE (512..1535) + Q trig table (>=1536) ----
__global__ void rope_vtrans(u16* __restrict__ qkv, u16* __restrict__ vt,
                            f32x4v* __restrict__ ctab, const int* __restrict__ pos) {
    __shared__ alignas(16) u16 sT[64 * 72];
    const int t = threadIdx.x;
    const float c0 = 0.20762050593045702f;       // log2(10000)/64
    if (blockIdx.x < 512) {
        const int f = blockIdx.x;
        const int t0 = (f & 31) * 64;
        const int d0 = ((f >> 5) & 1) * 64;
        const int kh = (f >> 6) & 3, b = f >> 8;
#pragma unroll
        for (int i = 0; i < 2; i++) {
            int tr = i * 32 + (t >> 3), dc = (t & 7) * 8;
            *(u16x8*)&sT[tr * 72 + dc] =
                *(const u16x8*)&qkv[(size_t)(b * T_SEQ + t0 + tr) * 3072 + 2560 + kh * 128 + d0 + dc];
        }
        __syncthreads();
#pragma unroll
        for (int i = 0; i < 2; i++) {
            int dr = i * 32 + (t >> 3), tc = (t & 7) * 8;
            u16x8 v;
#pragma unroll
            for (int j = 0; j < 8; j++) v[j] = sT[(tc + j) * 72 + dr];
            *(u16x8*)&vt[((size_t)(b * 4 + kh) * 128 + d0 + dr) * 2048 + t0 + tc] = v;
        }
    } else if (blockIdx.x < 1536) {
        // rope on K heads only: 4 slices (cols 2048..2560), 16 threads per (row, slice)
        int tid = (blockIdx.x - 512) * 256 + t;
        int j4 = tid & 15;
        int rest = tid >> 4;
        int slice = rest & 3;
        int row = rest >> 2;
        if (row >= 2 * T_SEQ) return;
        float tpos = (float)((row % T_SEQ) + pos[0]);
        int base = 2048 + slice * 128;
        u16* p = qkv + (size_t)row * 3072 + base + j4 * 4;
        u16x4 lo = *(const u16x4*)p;
        u16x4 hi = *(const u16x4*)(p + 64);
        u16x4 olo, ohi;
#pragma unroll
        for (int e = 0; e < 4; e++) {
            int i = (j4 * 4 + e) >> 1;
            float fA = tpos * exp2f(-(float)i * c0);
            float fB = tpos * exp2f(-(float)(32 + i) * c0);
            float x1 = bf2f(lo[e]), x2 = bf2f(hi[e]);
            olo[e] = f2bf(x1 * cosf(fA) - x2 * sinf(fA));
            ohi[e] = f2bf(x2 * cosf(fB) + x1 * sinf(fB));
        }
        *(u16x4*)p = olo;
        *(u16x4*)(p + 64) = ohi;
    } else {
        // Q trig table: ctab[qrow][i] = (cosA, sinA, cosB, sinB); 65536 threads
        int tid = (blockIdx.x - 1536) * 256 + t;
        int qrow = tid >> 5, i = tid & 31;
        float tpos = (float)(qrow + pos[0]);
        float fA = tpos * exp2f(-(float)i * c0);
        float fB = tpos * exp2f(-(float)(32 + i) * c0);
        f32x4v w;
        w.x = cosf(fA); w.y = sinf(fA); w.z = cosf(fB); w.w = sinf(fB);
        ctab[tid] = w;
    }
}

// ---------------- causal GQA flash attention: 8 waves x 16 q-rows ----------------
// R16-proven structure; Q-RoPE applied in registers via precomputed trig table
// (pairs lane-local: d = c*32+hl*8+e pairs with d+64 at c+2; i = c*16+hl*4+(e>>1)).
__global__ __launch_bounds__(512, 4) void attn(const u16* __restrict__ qkv,
                                               const u16* __restrict__ vt,
                                               u16* __restrict__ out,
                                               const f32x4v* __restrict__ ctab) {
    __shared__ alignas(16) u16 sK[2][8192];       // [64][128] XOR-swizzled content
    __shared__ alignas(16) u16 sV[8192];          // [128][64] XOR-swizzled content
    __shared__ alignas(16) __bf16 sP[128 * 72];
    const int t = threadIdx.x, wave = t >> 6, lane = t & 63;
    const int l15 = lane & 15, hl = lane >> 4;

    const int f = blockIdx.x;
    const int sel = f >> 8, u = f & 255;
    const int bkh = u & 7, b = bkh >> 2, kh = bkh & 3;
    const int h = kh * 4 + ((u >> 3) & 3);
    const int j = u >> 5;
    const int a = sel ? (15 - j) : j;
    const int q0 = a * 128;
    const int nt = 2 * a + 2;

    const float sc = 0.08838834764831845f;

    // Q fragments: load raw, RoPE via table, pre-scale
    const int qrow = q0 + wave * 16 + l15;
    u16x8 raw[4];
#pragma unroll
    for (int c = 0; c < 4; c++)
        raw[c] = *(const u16x8*)(qkv + (size_t)(b * T_SEQ + qrow) * 3072
                                 + h * 128 + c * 32 + hl * 8);
    const f32x4v* ct = ctab + (size_t)qrow * 32;
    u16x8 qv[4];
#pragma unroll
    for (int c = 0; c < 2; c++)
#pragma unroll
        for (int k = 0; k < 4; k++) {
            f32x4v w = ct[c * 16 + hl * 4 + k];   // cosA, sinA, cosB, sinB
#pragma unroll
            for (int par = 0; par < 2; par++) {
                int e = k * 2 + par;
                float x1 = bf2f(raw[c][e]), x2 = bf2f(raw[c + 2][e]);
                qv[c][e]     = f2bf((x1 * w.x - x2 * w.y) * sc);
                qv[c + 2][e] = f2bf((x2 * w.z + x1 * w.w) * sc);
            }
        }
    bf16x8 qf[4];
#pragma unroll
    for (int c = 0; c < 4; c++) qf[c] = *(bf16x8*)&qv[c];

    u16x8 onesu;
#pragma unroll
    for (int e = 0; e < 8; e++) onesu[e] = 0x3F80;
    const bf16x8 onesf = *(bf16x8*)&onesu;

    float mrow[4];
    f32x4 o[8];
    f32x4 osum;
    f32x4 z = {0.f, 0.f, 0.f, 0.f};
#pragma unroll
    for (int r = 0; r < 4; r++) mrow[r] = -1e30f;
    osum = z;
#pragma unroll
    for (int n8 = 0; n8 < 8; n8++) o[n8] = z;

    asm volatile("s_waitcnt vmcnt(0)" ::: "memory");

    const u16* kgbase = qkv + (size_t)(b * T_SEQ) * 3072 + 2048 + kh * 128;
    const u16* vgbase = vt + (size_t)(b * 4 + kh) * 128 * 2048;

#pragma unroll
    for (int p = 0; p < 2; p++) {
        int i = p * 512 + t;
        int row = i >> 4, c = i & 15;
        gload_lds16(kgbase + (size_t)row * 3072 + ((c ^ (row & 7)) * 8), (u16*)sK[0] + i * 8);
    }

    int cur = 0;
    for (int it = 0; it < nt; ++it) {
        const int kv0 = it * 64;
        const int kvn = (it + 1 < nt) ? kv0 + 64 : kv0;
#pragma unroll
        for (int p = 0; p < 2; p++) {
            int i = p * 512 + t;
            int row = i >> 3, c = i & 7;
            gload_lds16(vgbase + (size_t)row * 2048 + kv0 + ((c ^ (row & 7)) * 8), sV + i * 8);
        }
#pragma unroll
        for (int p = 0; p < 2; p++) {
            int i = p * 512 + t;
            int row = i >> 4, c = i & 15;
            gload_lds16(kgbase + (size_t)(kvn + row) * 3072 + ((c ^ (row & 7)) * 8),
                        (u16*)sK[cur ^ 1] + i * 8);
        }
        asm volatile("s_waitcnt vmcnt(4)" ::: "memory");   // K(t) landed
        __builtin_amdgcn_s_barrier();

        // S = Q K^T  (16 rows x 64 cols per wave)
        f32x4 sA[4];
#pragma unroll
        for (int n = 0; n < 4; n++) sA[n] = z;
#pragma unroll
        for (int n = 0; n < 4; n++)
#pragma unroll
            for (int c = 0; c < 4; c++) {
                int row = n * 16 + l15;
                bf16x8 kf = *(const bf16x8*)&sK[cur][row * 128 + (((c * 4 + hl) ^ (row & 7)) * 8)];
                sA[n] = __builtin_amdgcn_mfma_f32_16x16x32_bf16(qf[c], kf, sA[n], 0, 0, 0);
            }

        // online softmax: interior tiles skip causal mask entirely (wave-uniform)
        const bool full = (kv0 + 63 <= q0 + wave * 16);
        if (full) {
#pragma unroll
            for (int r = 0; r < 4; r++) {
                float pmax = fmaxf(fmaxf(sA[0][r], sA[1][r]), fmaxf(sA[2][r], sA[3][r]));
                if (__builtin_expect(__any(pmax > mrow[r] + 8.f), 0)) {
                    float mx = pmax;
#pragma unroll
                    for (int off = 1; off < 16; off <<= 1) mx = fmaxf(mx, __shfl_xor(mx, off));
                    float mnew = fmaxf(mrow[r], mx);
                    float alpha = __expf(mrow[r] - mnew);
                    mrow[r] = mnew;
#pragma unroll
                    for (int n8 = 0; n8 < 8; n8++) o[n8][r] *= alpha;
                    osum[r] *= alpha;
                }
#pragma unroll
                for (int n = 0; n < 4; n++)
                    sP[(wave * 16 + hl * 4 + r) * 72 + n * 16 + l15] =
                        (__bf16)__expf(sA[n][r] - mrow[r]);
            }
        } else {
#pragma unroll
            for (int r = 0; r < 4; r++) {
                const int grow = q0 + wave * 16 + hl * 4 + r;
                float mv[4];
#pragma unroll
                for (int n = 0; n < 4; n++)
                    mv[n] = (kv0 + n * 16 + l15 <= grow) ? sA[n][r] : -1e30f;
                float pmax = fmaxf(fmaxf(mv[0], mv[1]), fmaxf(mv[2], mv[3]));
                if (__builtin_expect(__any(pmax > mrow[r] + 8.f), 0)) {
                    float mx = pmax;
#pragma unroll
                    for (int off = 1; off < 16; off <<= 1) mx = fmaxf(mx, __shfl_xor(mx, off));
                    float mnew = fmaxf(mrow[r], mx);
                    float alpha = __expf(mrow[r] - mnew);
                    mrow[r] = mnew;
#pragma unroll
                    for (int n8 = 0; n8 < 8; n8++) o[n8][r] *= alpha;
                    osum[r] *= alpha;
                }
#pragma unroll
                for (int n = 0; n < 4; n++)
                    sP[(wave * 16 + hl * 4 + r) * 72 + n * 16 + l15] =
                        (__bf16)__expf(mv[n] - mrow[r]);
            }
        }

        asm volatile("s_waitcnt vmcnt(2)" ::: "memory");   // V(t) landed
        __builtin_amdgcn_s_barrier();

        bf16x8 pa[2];
#pragma unroll
        for (int k2 = 0; k2 < 2; k2++)
            pa[k2] = *(const bf16x8*)&sP[(wave * 16 + l15) * 72 + k2 * 32 + hl * 8];
#pragma unroll
        for (int k2 = 0; k2 < 2; k2++)
            osum = __builtin_amdgcn_mfma_f32_16x16x32_bf16(pa[k2], onesf, osum, 0, 0, 0);
#pragma unroll
        for (int n8 = 0; n8 < 8; n8++)
#pragma unroll
            for (int k2 = 0; k2 < 2; k2++) {
                int d = n8 * 16 + l15;
                bf16x8 vf = *(const bf16x8*)&sV[d * 64 + (((k2 * 4 + hl) ^ (d & 7)) * 8)];
                o[n8] = __builtin_amdgcn_mfma_f32_16x16x32_bf16(pa[k2], vf, o[n8], 0, 0, 0);
            }
        __builtin_amdgcn_s_barrier();
        cur ^= 1;
    }

#pragma unroll
    for (int r = 0; r < 4; r++) {
        float inv = 1.f / osum[r];
        int orow = b * T_SEQ + q0 + wave * 16 + hl * 4 + r;
#pragma unroll
        for (int n8 = 0; n8 < 8; n8++)
            out[(size_t)orow * 2048 + h * 128 + n8 * 16 + l15] = f2bf(o[n8][r] * inv);
    }
}

extern "C" void kernel_launch(void* const* d_in, const int* in_sizes, int n_in,
                              void* d_out, int out_size, void* d_ws, size_t ws_size,
                              hipStream_t stream) {
    const float* x  = (const float*)d_in[0];
    const float* Wq = (const float*)d_in[1];
    const float* Wk = (const float*)d_in[2];
    const float* Wv = (const float*)d_in[3];
    const float* Wp = (const float*)d_in[4];
    const int*   pos = (const int*)d_in[5];

    char* ws = (char*)d_ws;
    u16* xbf   = (u16*)(ws);                        // 4096*2048 bf16 (dead after gemm_qkv; reused for ctab)
    u16* WtQKV = (u16*)(ws + 16777216);             // 3072*2048 bf16
    u16* WtP   = (u16*)(ws + 29360128);             // 2048*2048 bf16
    u16* QKV   = (u16*)(ws + 37748736);             // 4096*3072 bf16
    u16* Vt    = (u16*)(ws + 62914560);             // 2*4*128*2048 bf16
    u16* AO    = (u16*)(ws + 67108864);             // 4096*2048 bf16
    f32x4v* ctab = (f32x4v*)(ws);                   // 2048*32 float4 = 1 MB (in dead xbf region)

    prep_all<<<4096 + 2560, 256, 0, stream>>>(x, xbf, Wq, Wk, Wv, Wp, WtQKV, WtP);
    gemm_qkv<<<256, 512, 0, stream>>>(xbf, WtQKV, QKV, 4096, 3072, 2048);
    rope_vtrans<<<512 + 1024 + 256, 256, 0, stream>>>(QKV, Vt, ctab, pos);
    attn<<<512, 512, 0, stream>>>(QKV, Vt, AO, ctab);
    gemm_proj<<<256, 512, 0, stream>>>(AO, WtP, (float*)d_out, 4096, 2048, 2048);
}